// Round 1
// baseline (2987.001 us; speedup 1.0000x reference)
//
#include <hip/hip_runtime.h>
#include <math.h>

#define HIDDEN 2048
#define HARM   64
#define NHEADS 16
#define HDIM   128
#define SEQ    2048
#define BATCH  2
#define ROWS   (BATCH*SEQ)   // 4096

// ---------------------------------------------------------------- w = amp*cos(phase)
__global__ __launch_bounds__(256) void w_kernel(
    const float* __restrict__ pq, const float* __restrict__ aq,
    const float* __restrict__ pk, const float* __restrict__ ak,
    const float* __restrict__ pv, const float* __restrict__ av,
    const float* __restrict__ po, const float* __restrict__ ao,
    float* __restrict__ W) {
  int i = blockIdx.x * 256 + threadIdx.x;
  const int N = HIDDEN * HARM;
  if (i >= 4 * N) return;
  int set = i / N, j = i - set * N;
  const float* p = (set == 0) ? pq : (set == 1) ? pk : (set == 2) ? pv : po;
  const float* a = (set == 0) ? aq : (set == 1) ? ak : (set == 2) ? av : ao;
  W[i] = a[j] * cosf(p[j]);
}

// ------------------------------------------- R[M x 64] = X[M x 2048] * B[64 x 2048]^T
// block: 64 rows x 64 harmonics, K-chunks of 32. 256 thr, 4x4 micro-tile.
__global__ __launch_bounds__(256) void resonance_kernel(
    const float* __restrict__ X, const float* __restrict__ B,
    float* __restrict__ R) {
  const int row0 = blockIdx.x * 64;
  __shared__ float Xs[64][33];
  __shared__ float Bs[64][33];
  const int tid = threadIdx.x;
  const int ty = tid >> 4, tx = tid & 15;
  float acc[4][4] = {};
  for (int k0 = 0; k0 < HIDDEN; k0 += 32) {
    for (int i = 0; i < 8; ++i) {
      int idx = tid + i * 256;
      int r = idx >> 5, kk = idx & 31;
      Xs[r][kk] = X[(size_t)(row0 + r) * HIDDEN + k0 + kk];
      Bs[r][kk] = B[(size_t)r * HIDDEN + k0 + kk];
    }
    __syncthreads();
    for (int kk = 0; kk < 32; ++kk) {
      float xv[4], bv[4];
      #pragma unroll
      for (int i = 0; i < 4; ++i) xv[i] = Xs[ty * 4 + i][kk];
      #pragma unroll
      for (int j = 0; j < 4; ++j) bv[j] = Bs[tx + 16 * j][kk];  // stride-16 cols: conflict-free
      #pragma unroll
      for (int i = 0; i < 4; ++i)
        #pragma unroll
        for (int j = 0; j < 4; ++j) acc[i][j] += xv[i] * bv[j];
    }
    __syncthreads();
  }
  for (int i = 0; i < 4; ++i)
    for (int j = 0; j < 4; ++j)
      R[(size_t)(row0 + ty * 4 + i) * HARM + tx + 16 * j] = acc[i][j];
}

// ------------------------------------ P[M x 2048] = R[M x 64] * W[2048 x 64]^T (K=64)
// block: 32 rows x 128 cols. 256 thr, 4x4 micro-tile.
__global__ __launch_bounds__(256) void proj_kernel(
    const float* __restrict__ R, const float* __restrict__ W,
    float* __restrict__ P) {
  const int row0 = blockIdx.x * 32;
  const int col0 = blockIdx.y * 128;
  __shared__ float Rs[32][65];
  __shared__ float Ws[128][65];
  const int tid = threadIdx.x;
  for (int i = 0; i < 8; ++i) {
    int idx = tid + i * 256;
    int r = idx >> 6, kk = idx & 63;
    Rs[r][kk] = R[(size_t)(row0 + r) * HARM + kk];
  }
  for (int i = 0; i < 32; ++i) {
    int idx = tid + i * 256;
    int c = idx >> 6, kk = idx & 63;
    Ws[c][kk] = W[(size_t)(col0 + c) * HARM + kk];
  }
  __syncthreads();
  const int ty = tid >> 5, tx = tid & 31;
  float acc[4][4] = {};
  for (int kk = 0; kk < 64; ++kk) {
    float rv[4], wv[4];
    #pragma unroll
    for (int i = 0; i < 4; ++i) rv[i] = Rs[ty * 4 + i][kk];
    #pragma unroll
    for (int j = 0; j < 4; ++j) wv[j] = Ws[tx + 32 * j][kk];  // stride-32 cols: conflict-free
    #pragma unroll
    for (int i = 0; i < 4; ++i)
      #pragma unroll
      for (int j = 0; j < 4; ++j) acc[i][j] += rv[i] * wv[j];
  }
  for (int i = 0; i < 4; ++i)
    for (int j = 0; j < 4; ++j)
      P[(size_t)(row0 + ty * 4 + i) * HIDDEN + col0 + tx + 32 * j] = acc[i][j];
}

// ----------------------------------------------------- flash attention, fp32 baseline
// one block per (b,h, 32-q-tile); 32-key chunks; online softmax. Q/K/V layout:
// buf[b*SEQ + s][h*HDIM + d]  (i.e., the natural (B,S,HIDDEN) projection output).
__global__ __launch_bounds__(256) void attn_kernel(
    const float* __restrict__ Q, const float* __restrict__ K,
    const float* __restrict__ V, float* __restrict__ O) {
  const int b = blockIdx.x >> 4, h = blockIdx.x & 15;
  const int q0 = blockIdx.y * 32;
  const float scale = 0.08838834764831845f;  // 1/sqrt(128)
  __shared__ float Qs[32][129];   // +1 pad: conflict-free row-pair reads
  __shared__ float Ks[32][129];
  __shared__ float Vs[32][128];
  __shared__ float Ss[32][33];
  __shared__ float alpha_s[32], m_s[32], l_s[32];
  const int tid = threadIdx.x;
  const size_t base = (size_t)b * SEQ * HIDDEN + (size_t)h * HDIM;
  for (int i = 0; i < 16; ++i) {
    int idx = tid + i * 256;
    int r = idx >> 7, d = idx & 127;
    Qs[r][d] = Q[base + (size_t)(q0 + r) * HIDDEN + d] * scale;
  }
  if (tid < 32) { m_s[tid] = -1e30f; l_s[tid] = 0.0f; }
  float oacc[16];
  #pragma unroll
  for (int i = 0; i < 16; ++i) oacc[i] = 0.0f;
  const int oqi = tid >> 3;              // q row this thread accumulates
  const int od0 = (tid & 7) * 16;        // 16 contiguous d per thread
  __syncthreads();

  for (int k0 = 0; k0 < SEQ; k0 += 32) {
    for (int i = 0; i < 16; ++i) {
      int idx = tid + i * 256;
      int r = idx >> 7, d = idx & 127;
      Ks[r][d] = K[base + (size_t)(k0 + r) * HIDDEN + d];
      Vs[r][d] = V[base + (size_t)(k0 + r) * HIDDEN + d];
    }
    __syncthreads();
    // --- scores: each thread a 2x2 micro-tile of the 32x32 S
    {
      const int qi = (tid >> 4) * 2, ki = (tid & 15) * 2;
      float a00 = 0.f, a01 = 0.f, a10 = 0.f, a11 = 0.f;
      const float* qa = Qs[qi];
      const float* qb = Qs[qi + 1];
      const float* ka = Ks[ki];
      const float* kb = Ks[ki + 1];
      for (int d = 0; d < HDIM; ++d) {
        float x0 = qa[d], x1 = qb[d], y0 = ka[d], y1 = kb[d];
        a00 += x0 * y0; a01 += x0 * y1; a10 += x1 * y0; a11 += x1 * y1;
      }
      Ss[qi][ki] = a00;     Ss[qi][ki + 1] = a01;
      Ss[qi + 1][ki] = a10; Ss[qi + 1][ki + 1] = a11;
    }
    __syncthreads();
    // --- online softmax update (one thread per q row)
    if (tid < 32) {
      float m_old = m_s[tid];
      float mx = m_old;
      for (int j = 0; j < 32; ++j) mx = fmaxf(mx, Ss[tid][j]);
      float al = __expf(m_old - mx);
      float sum = 0.0f;
      for (int j = 0; j < 32; ++j) {
        float p = __expf(Ss[tid][j] - mx);
        Ss[tid][j] = p;
        sum += p;
      }
      m_s[tid] = mx;
      l_s[tid] = l_s[tid] * al + sum;
      alpha_s[tid] = al;
    }
    __syncthreads();
    // --- O = O*alpha + P @ V-chunk
    {
      float al = alpha_s[oqi];
      #pragma unroll
      for (int i = 0; i < 16; ++i) oacc[i] *= al;
      for (int ki = 0; ki < 32; ++ki) {
        float p = Ss[oqi][ki];
        const float* vp = &Vs[ki][od0];
        #pragma unroll
        for (int i = 0; i < 16; ++i) oacc[i] += p * vp[i];
      }
    }
    __syncthreads();
  }
  const float inv_l = 1.0f / l_s[oqi];
  const size_t ob = base + (size_t)(q0 + oqi) * HIDDEN + od0;
  for (int i = 0; i < 16; ++i) O[ob + i] = oacc[i] * inv_l;
}

// -------------------------------------------------------------------------- launcher
extern "C" void kernel_launch(void* const* d_in, const int* in_sizes, int n_in,
                              void* d_out, int out_size, void* d_ws, size_t ws_size,
                              hipStream_t stream) {
  (void)in_sizes; (void)n_in; (void)out_size; (void)ws_size;
  const float* X       = (const float*)d_in[0];
  const float* basis_q = (const float*)d_in[1];
  const float* phase_q = (const float*)d_in[2];
  const float* amp_q   = (const float*)d_in[3];
  const float* basis_k = (const float*)d_in[4];
  const float* phase_k = (const float*)d_in[5];
  const float* amp_k   = (const float*)d_in[6];
  const float* basis_v = (const float*)d_in[7];
  const float* phase_v = (const float*)d_in[8];
  const float* amp_v   = (const float*)d_in[9];
  const float* basis_o = (const float*)d_in[10];
  const float* phase_o = (const float*)d_in[11];
  const float* amp_o   = (const float*)d_in[12];

  float* ws = (float*)d_ws;
  const size_t WN = (size_t)HIDDEN * HARM;   // 131072
  const size_t RN = (size_t)ROWS * HARM;     // 262144
  const size_t PN = (size_t)ROWS * HIDDEN;   // 8388608
  float* Wq = ws;
  float* Wk = Wq + WN;
  float* Wv = Wk + WN;
  float* Wo = Wv + WN;
  float* Rq = Wo + WN;
  float* Rk = Rq + RN;
  float* Rv = Rk + RN;
  float* Qb = Rv + RN;
  float* Kb = Qb + PN;
  float* Vb = Kb + PN;
  float* AO = Vb + PN;                       // total ~139.5 MB of ws
  float* out = (float*)d_out;

  w_kernel<<<(int)((4 * WN + 255) / 256), 256, 0, stream>>>(
      phase_q, amp_q, phase_k, amp_k, phase_v, amp_v, phase_o, amp_o, Wq);

  resonance_kernel<<<ROWS / 64, 256, 0, stream>>>(X, basis_q, Rq);
  resonance_kernel<<<ROWS / 64, 256, 0, stream>>>(X, basis_k, Rk);
  resonance_kernel<<<ROWS / 64, 256, 0, stream>>>(X, basis_v, Rv);

  dim3 pg(ROWS / 32, HIDDEN / 128);
  proj_kernel<<<pg, 256, 0, stream>>>(Rq, Wq, Qb);
  proj_kernel<<<pg, 256, 0, stream>>>(Rk, Wk, Kb);
  proj_kernel<<<pg, 256, 0, stream>>>(Rv, Wv, Vb);

  dim3 ag(BATCH * NHEADS, SEQ / 32);
  attn_kernel<<<ag, 256, 0, stream>>>(Qb, Kb, Vb, AO);

  resonance_kernel<<<ROWS / 64, 256, 0, stream>>>(AO, basis_o, Rq);  // reuse Rq
  proj_kernel<<<pg, 256, 0, stream>>>(Rq, Wo, out);
}

// Round 2
// 1031.434 us; speedup vs baseline: 2.8960x; 2.8960x over previous
//
#include <hip/hip_runtime.h>
#include <hip/hip_bf16.h>
#include <math.h>

#define HIDDEN 2048
#define HARM   64
#define NHEADS 16
#define HDIM   128
#define SEQ    2048
#define BATCH  2
#define ROWS   (BATCH*SEQ)   // 4096

using bf16x8 = __attribute__((ext_vector_type(8))) short;
using f32x16 = __attribute__((ext_vector_type(16))) float;

// ---------------------------------------------------------------- w = amp*cos(phase)
__global__ __launch_bounds__(256) void w_kernel(
    const float* __restrict__ pq, const float* __restrict__ aq,
    const float* __restrict__ pk, const float* __restrict__ ak,
    const float* __restrict__ pv, const float* __restrict__ av,
    const float* __restrict__ po, const float* __restrict__ ao,
    float* __restrict__ W) {
  int i = blockIdx.x * 256 + threadIdx.x;
  const int N = HIDDEN * HARM;
  if (i >= 4 * N) return;
  int set = i / N, j = i - set * N;
  const float* p = (set == 0) ? pq : (set == 1) ? pk : (set == 2) ? pv : po;
  const float* a = (set == 0) ? aq : (set == 1) ? ak : (set == 2) ? av : ao;
  W[i] = a[j] * cosf(p[j]);
}

// ------------------------------------------- R[M x 64] = X[M x 2048] * B[64 x 2048]^T
__global__ __launch_bounds__(256) void resonance_kernel(
    const float* __restrict__ X, const float* __restrict__ B,
    float* __restrict__ R) {
  const int row0 = blockIdx.x * 64;
  __shared__ float Xs[64][33];
  __shared__ float Bs[64][33];
  const int tid = threadIdx.x;
  const int ty = tid >> 4, tx = tid & 15;
  float acc[4][4] = {};
  for (int k0 = 0; k0 < HIDDEN; k0 += 32) {
    for (int i = 0; i < 8; ++i) {
      int idx = tid + i * 256;
      int r = idx >> 5, kk = idx & 31;
      Xs[r][kk] = X[(size_t)(row0 + r) * HIDDEN + k0 + kk];
      Bs[r][kk] = B[(size_t)r * HIDDEN + k0 + kk];
    }
    __syncthreads();
    for (int kk = 0; kk < 32; ++kk) {
      float xv[4], bv[4];
      #pragma unroll
      for (int i = 0; i < 4; ++i) xv[i] = Xs[ty * 4 + i][kk];
      #pragma unroll
      for (int j = 0; j < 4; ++j) bv[j] = Bs[tx + 16 * j][kk];
      #pragma unroll
      for (int i = 0; i < 4; ++i)
        #pragma unroll
        for (int j = 0; j < 4; ++j) acc[i][j] += xv[i] * bv[j];
    }
    __syncthreads();
  }
  for (int i = 0; i < 4; ++i)
    for (int j = 0; j < 4; ++j)
      R[(size_t)(row0 + ty * 4 + i) * HARM + tx + 16 * j] = acc[i][j];
}

// ------------------------------------ P[M x 2048] = R[M x 64] * W[2048 x 64]^T (K=64)
// fp32-output variant (final projection)
__global__ __launch_bounds__(256) void proj_kernel(
    const float* __restrict__ R, const float* __restrict__ W,
    float* __restrict__ P) {
  const int row0 = blockIdx.x * 32;
  const int col0 = blockIdx.y * 128;
  __shared__ float Rs[32][65];
  __shared__ float Ws[128][65];
  const int tid = threadIdx.x;
  for (int i = 0; i < 8; ++i) {
    int idx = tid + i * 256;
    int r = idx >> 6, kk = idx & 63;
    Rs[r][kk] = R[(size_t)(row0 + r) * HARM + kk];
  }
  for (int i = 0; i < 32; ++i) {
    int idx = tid + i * 256;
    int c = idx >> 6, kk = idx & 63;
    Ws[c][kk] = W[(size_t)(col0 + c) * HARM + kk];
  }
  __syncthreads();
  const int ty = tid >> 5, tx = tid & 31;
  float acc[4][4] = {};
  for (int kk = 0; kk < 64; ++kk) {
    float rv[4], wv[4];
    #pragma unroll
    for (int i = 0; i < 4; ++i) rv[i] = Rs[ty * 4 + i][kk];
    #pragma unroll
    for (int j = 0; j < 4; ++j) wv[j] = Ws[tx + 32 * j][kk];
    #pragma unroll
    for (int i = 0; i < 4; ++i)
      #pragma unroll
      for (int j = 0; j < 4; ++j) acc[i][j] += rv[i] * wv[j];
  }
  for (int i = 0; i < 4; ++i)
    for (int j = 0; j < 4; ++j)
      P[(size_t)(row0 + ty * 4 + i) * HIDDEN + col0 + tx + 32 * j] = acc[i][j];
}

// bf16-output variant (Q/K/V projections feeding MFMA attention)
__global__ __launch_bounds__(256) void proj_bf16_kernel(
    const float* __restrict__ R, const float* __restrict__ W,
    __hip_bfloat16* __restrict__ P) {
  const int row0 = blockIdx.x * 32;
  const int col0 = blockIdx.y * 128;
  __shared__ float Rs[32][65];
  __shared__ float Ws[128][65];
  const int tid = threadIdx.x;
  for (int i = 0; i < 8; ++i) {
    int idx = tid + i * 256;
    int r = idx >> 6, kk = idx & 63;
    Rs[r][kk] = R[(size_t)(row0 + r) * HARM + kk];
  }
  for (int i = 0; i < 32; ++i) {
    int idx = tid + i * 256;
    int c = idx >> 6, kk = idx & 63;
    Ws[c][kk] = W[(size_t)(col0 + c) * HARM + kk];
  }
  __syncthreads();
  const int ty = tid >> 5, tx = tid & 31;
  float acc[4][4] = {};
  for (int kk = 0; kk < 64; ++kk) {
    float rv[4], wv[4];
    #pragma unroll
    for (int i = 0; i < 4; ++i) rv[i] = Rs[ty * 4 + i][kk];
    #pragma unroll
    for (int j = 0; j < 4; ++j) wv[j] = Ws[tx + 32 * j][kk];
    #pragma unroll
    for (int i = 0; i < 4; ++i)
      #pragma unroll
      for (int j = 0; j < 4; ++j) acc[i][j] += rv[i] * wv[j];
  }
  for (int i = 0; i < 4; ++i)
    for (int j = 0; j < 4; ++j)
      P[(size_t)(row0 + ty * 4 + i) * HIDDEN + col0 + tx + 32 * j] =
          __float2bfloat16(acc[i][j]);
}

// -------------------------------------- per-batch 2048x2048 bf16 transpose (V -> V^T)
// Vt[b*2048 + hidcol][token] = Vb[b*2048 + token][hidcol]
__global__ __launch_bounds__(256) void transpose_v(
    const ushort* __restrict__ S, ushort* __restrict__ D) {
  const int b = blockIdx.z;
  const int r0 = blockIdx.y * 32, c0 = blockIdx.x * 32;
  __shared__ ushort tile[32][33];
  const int t = threadIdx.x;
  const int r = t >> 3, cs = (t & 7) * 4;
  const ushort* Sb = S + (size_t)b * SEQ * HIDDEN;
  ushort* Db = D + (size_t)b * SEQ * HIDDEN;
  ushort4 v = *(const ushort4*)&Sb[(size_t)(r0 + r) * HIDDEN + c0 + cs];
  tile[r][cs] = v.x; tile[r][cs + 1] = v.y; tile[r][cs + 2] = v.z; tile[r][cs + 3] = v.w;
  __syncthreads();
  ushort4 o;
  o.x = tile[cs + 0][r]; o.y = tile[cs + 1][r];
  o.z = tile[cs + 2][r]; o.w = tile[cs + 3][r];
  *(ushort4*)&Db[(size_t)(c0 + r) * SEQ + r0 + cs] = o;
}

// ----------------------------------------------------------- MFMA flash attention
// Grid: 512 blocks = qt*32 + bh  (bh -> XCD affinity via blockIdx%8).
// Block: 4 waves x 32 q rows = 128 q rows. Chunks of 64 keys.
// S^T via mfma (A=K, B=Q): C-layout col = q = lane&31, row = key.
// PV as O^T = V^T P^T: A2 = V^T tile (LDS), B2 = P^T built in-register from the
// S^T C-layout with one half-wave shfl_xor(32) exchange per k-step.
#define BQ 128
#define BK 64
#define KSTR 136   // Qs/Ks row stride (ushorts): 272B = 17*16, bank-adv 4 words
#define VSTR 72    // Vs row stride (ushorts): 144B = 9*16

__device__ inline unsigned pkbf(float a, float b) {
  __hip_bfloat162 h2 = __float22bfloat162_rn(make_float2(a, b));
  union { __hip_bfloat162 h; unsigned u; } cv; cv.h = h2; return cv.u;
}

__global__ __launch_bounds__(256, 2) void attn_mfma(
    const ushort* __restrict__ Qg, const ushort* __restrict__ Kg,
    const ushort* __restrict__ Vt, float* __restrict__ O) {
  __shared__ __align__(16) union SM {
    ushort q[BQ][KSTR];                                    // 34816 B
    struct { ushort k[BK][KSTR]; ushort v[HDIM][VSTR]; } kv;  // 17408+18432 B
  } sm;
  const int t = threadIdx.x;
  const int bh = blockIdx.x & 31;
  const int qt = blockIdx.x >> 5;
  const int b = bh >> 4, h = bh & 15;
  const int q0 = qt * BQ;
  const int lane = t & 63;
  const int w = t >> 6;
  const int l31 = lane & 31;
  const int hh = lane >> 5;
  const float SC2 = 0.08838834764831845f * 1.4426950408889634f;  // scale * log2(e)

  // ---- stage Q tile (128 x 128 bf16) and pull B-fragments into registers
  {
    const size_t gbase = ((size_t)(b * SEQ + q0)) * HIDDEN + h * HDIM;
    for (int p = 0; p < 8; ++p) {
      int row = p * 16 + (t >> 4);
      int d0 = (t & 15) * 8;
      uint4 v = *(const uint4*)&Qg[gbase + (size_t)row * HIDDEN + d0];
      *(uint4*)&sm.q[row][d0] = v;
    }
  }
  __syncthreads();
  bf16x8 Qf[8];
  {
    const int qrow = w * 32 + l31;
    #pragma unroll
    for (int ks = 0; ks < 8; ++ks)
      Qf[ks] = *(const bf16x8*)&sm.q[qrow][ks * 16 + 8 * hh];
  }
  __syncthreads();

  float mrow = -1e30f, lsum = 0.0f;
  f32x16 Ot[4];
  #pragma unroll
  for (int i = 0; i < 4; ++i)
    #pragma unroll
    for (int j = 0; j < 16; ++j) Ot[i][j] = 0.0f;

  for (int k0 = 0; k0 < SEQ; k0 += BK) {
    // ---- stage K chunk (64 keys x 128 d) and V^T chunk (128 d x 64 keys)
    {
      const size_t gb = ((size_t)(b * SEQ + k0)) * HIDDEN + h * HDIM;
      #pragma unroll
      for (int p = 0; p < 4; ++p) {
        int key = p * 16 + (t >> 4);
        int d0 = (t & 15) * 8;
        uint4 v = *(const uint4*)&Kg[gb + (size_t)key * HIDDEN + d0];
        *(uint4*)&sm.kv.k[key][d0] = v;
      }
      const size_t vb = ((size_t)(b * SEQ + h * HDIM)) * SEQ + k0;
      #pragma unroll
      for (int p = 0; p < 4; ++p) {
        int d = p * 32 + (t >> 3);
        int ks2 = (t & 7) * 8;
        uint4 v = *(const uint4*)&Vt[vb + (size_t)d * SEQ + ks2];
        *(uint4*)&sm.kv.v[d][ks2] = v;
      }
    }
    __syncthreads();

    // ---- S^T = K . Q^T   (two 32-key m-tiles)
    f32x16 C0, C1;
    #pragma unroll
    for (int j = 0; j < 16; ++j) { C0[j] = 0.0f; C1[j] = 0.0f; }
    #pragma unroll
    for (int ks = 0; ks < 8; ++ks) {
      bf16x8 a0 = *(const bf16x8*)&sm.kv.k[l31][ks * 16 + 8 * hh];
      bf16x8 a1 = *(const bf16x8*)&sm.kv.k[32 + l31][ks * 16 + 8 * hh];
      C0 = __builtin_amdgcn_mfma_f32_32x32x16_bf16(a0, Qf[ks], C0, 0, 0, 0);
      C1 = __builtin_amdgcn_mfma_f32_32x32x16_bf16(a1, Qf[ks], C1, 0, 0, 0);
    }

    // ---- online softmax (per lane = one q column; keys live in regs + partner half)
    float p2[2][16];
    float mx = -1e30f;
    #pragma unroll
    for (int j = 0; j < 16; ++j) {
      p2[0][j] = C0[j] * SC2;
      p2[1][j] = C1[j] * SC2;
      mx = fmaxf(mx, fmaxf(p2[0][j], p2[1][j]));
    }
    mx = fmaxf(mx, __shfl_xor(mx, 32));
    const float mnew = fmaxf(mrow, mx);
    const float alpha = exp2f(mrow - mnew);
    float ssum = 0.0f;
    #pragma unroll
    for (int j = 0; j < 16; ++j) {
      p2[0][j] = exp2f(p2[0][j] - mnew);
      p2[1][j] = exp2f(p2[1][j] - mnew);
      ssum += p2[0][j] + p2[1][j];
    }
    ssum += __shfl_xor(ssum, 32);
    lsum = lsum * alpha + ssum;
    mrow = mnew;
    #pragma unroll
    for (int i = 0; i < 4; ++i)
      #pragma unroll
      for (int j = 0; j < 16; ++j) Ot[i][j] *= alpha;

    // ---- O^T += V^T . P^T   (4 k-steps of 16 keys)
    #pragma unroll
    for (int st = 0; st < 4; ++st) {
      const int uo = 2 * st + hh, up = uo ^ 1;
      const float* po = &p2[uo >> 2][(uo & 3) * 4];
      const float* pp = &p2[up >> 2][(up & 3) * 4];
      unsigned so0 = pkbf(po[0], po[1]), so1 = pkbf(po[2], po[3]);
      unsigned sp0 = pkbf(pp[0], pp[1]), sp1 = pkbf(pp[2], pp[3]);
      unsigned r0 = (unsigned)__shfl_xor((int)sp0, 32);
      unsigned r1 = (unsigned)__shfl_xor((int)sp1, 32);
      union { unsigned u[4]; bf16x8 v; } cv;
      cv.u[0] = hh ? r0 : so0;
      cv.u[1] = hh ? r1 : so1;
      cv.u[2] = hh ? so0 : r0;
      cv.u[3] = hh ? so1 : r1;
      #pragma unroll
      for (int mt = 0; mt < 4; ++mt) {
        bf16x8 a2 = *(const bf16x8*)&sm.kv.v[mt * 32 + l31][st * 16 + 8 * hh];
        Ot[mt] = __builtin_amdgcn_mfma_f32_32x32x16_bf16(a2, cv.v, Ot[mt], 0, 0, 0);
      }
    }
    __syncthreads();
  }

  // ---- epilogue: O[q][d] = Ot/lsum ; C-layout rows are d, col is q
  const float inv = 1.0f / lsum;
  const int qrow = q0 + w * 32 + l31;
  float* ob = O + ((size_t)(b * SEQ + qrow)) * HIDDEN + h * HDIM;
  #pragma unroll
  for (int mt = 0; mt < 4; ++mt)
    #pragma unroll
    for (int g = 0; g < 4; ++g) {
      float4 vv = make_float4(Ot[mt][4 * g + 0] * inv, Ot[mt][4 * g + 1] * inv,
                              Ot[mt][4 * g + 2] * inv, Ot[mt][4 * g + 3] * inv);
      *(float4*)&ob[mt * 32 + 8 * g + 4 * hh] = vv;
    }
}

// -------------------------------------------------------------------------- launcher
extern "C" void kernel_launch(void* const* d_in, const int* in_sizes, int n_in,
                              void* d_out, int out_size, void* d_ws, size_t ws_size,
                              hipStream_t stream) {
  (void)in_sizes; (void)n_in; (void)out_size; (void)ws_size;
  const float* X       = (const float*)d_in[0];
  const float* basis_q = (const float*)d_in[1];
  const float* phase_q = (const float*)d_in[2];
  const float* amp_q   = (const float*)d_in[3];
  const float* basis_k = (const float*)d_in[4];
  const float* phase_k = (const float*)d_in[5];
  const float* amp_k   = (const float*)d_in[6];
  const float* basis_v = (const float*)d_in[7];
  const float* phase_v = (const float*)d_in[8];
  const float* amp_v   = (const float*)d_in[9];
  const float* basis_o = (const float*)d_in[10];
  const float* phase_o = (const float*)d_in[11];
  const float* amp_o   = (const float*)d_in[12];

  const size_t WN = (size_t)HIDDEN * HARM;   // 131072
  const size_t RN = (size_t)ROWS * HARM;     // 262144
  const size_t PN = (size_t)ROWS * HIDDEN;   // 8388608

  char* p = (char*)d_ws;
  float* Wq = (float*)p; p += WN * 4;
  float* Wk = (float*)p; p += WN * 4;
  float* Wv = (float*)p; p += WN * 4;
  float* Wo = (float*)p; p += WN * 4;
  float* Rq = (float*)p; p += RN * 4;
  float* Rk = (float*)p; p += RN * 4;
  float* Rv = (float*)p; p += RN * 4;
  __hip_bfloat16* Qb = (__hip_bfloat16*)p; p += PN * 2;
  __hip_bfloat16* Kb = (__hip_bfloat16*)p; p += PN * 2;
  __hip_bfloat16* Vb = (__hip_bfloat16*)p; p += PN * 2;
  __hip_bfloat16* VtB = (__hip_bfloat16*)p; p += PN * 2;
  float* AO = (float*)p; p += PN * 4;
  float* out = (float*)d_out;

  w_kernel<<<(int)((4 * WN + 255) / 256), 256, 0, stream>>>(
      phase_q, amp_q, phase_k, amp_k, phase_v, amp_v, phase_o, amp_o, Wq);

  resonance_kernel<<<ROWS / 64, 256, 0, stream>>>(X, basis_q, Rq);
  resonance_kernel<<<ROWS / 64, 256, 0, stream>>>(X, basis_k, Rk);
  resonance_kernel<<<ROWS / 64, 256, 0, stream>>>(X, basis_v, Rv);

  dim3 pg(ROWS / 32, HIDDEN / 128);
  proj_bf16_kernel<<<pg, 256, 0, stream>>>(Rq, Wq, Qb);
  proj_bf16_kernel<<<pg, 256, 0, stream>>>(Rk, Wk, Kb);
  proj_bf16_kernel<<<pg, 256, 0, stream>>>(Rv, Wv, Vb);

  dim3 tg(HIDDEN / 32, SEQ / 32, BATCH);
  transpose_v<<<tg, 256, 0, stream>>>((const ushort*)Vb, (ushort*)VtB);

  attn_mfma<<<dim3((SEQ / BQ) * 32), 256, 0, stream>>>(
      (const ushort*)Qb, (const ushort*)Kb, (const ushort*)VtB, AO);

  resonance_kernel<<<ROWS / 64, 256, 0, stream>>>(AO, basis_o, Rq);
  proj_kernel<<<pg, 256, 0, stream>>>(Rq, Wo, out);
}

// Round 3
// 842.938 us; speedup vs baseline: 3.5436x; 1.2236x over previous
//
#include <hip/hip_runtime.h>
#include <hip/hip_bf16.h>
#include <math.h>

#define HIDDEN 2048
#define HARM   64
#define NHEADS 16
#define HDIM   128
#define SEQ    2048
#define BATCH  2
#define ROWS   (BATCH*SEQ)   // 4096

using bf16x8 = __attribute__((ext_vector_type(8))) short;
using f32x16 = __attribute__((ext_vector_type(16))) float;

// ---------------------------------------------------------------- w = amp*cos(phase)
__global__ __launch_bounds__(256) void w_kernel(
    const float* __restrict__ pq, const float* __restrict__ aq,
    const float* __restrict__ pk, const float* __restrict__ ak,
    const float* __restrict__ pv, const float* __restrict__ av,
    const float* __restrict__ po, const float* __restrict__ ao,
    float* __restrict__ W) {
  int i = blockIdx.x * 256 + threadIdx.x;
  const int N = HIDDEN * HARM;
  if (i >= 4 * N) return;
  int set = i / N, j = i - set * N;
  const float* p = (set == 0) ? pq : (set == 1) ? pk : (set == 2) ? pv : po;
  const float* a = (set == 0) ? aq : (set == 1) ? ak : (set == 2) ? av : ao;
  W[i] = a[j] * cosf(p[j]);
}

// ------------------------------------------- R[M x 64] = X[M x 2048] * B[64 x 2048]^T
__global__ __launch_bounds__(256) void resonance_kernel(
    const float* __restrict__ X, const float* __restrict__ B,
    float* __restrict__ R) {
  const int row0 = blockIdx.x * 64;
  __shared__ float Xs[64][33];
  __shared__ float Bs[64][33];
  const int tid = threadIdx.x;
  const int ty = tid >> 4, tx = tid & 15;
  float acc[4][4] = {};
  for (int k0 = 0; k0 < HIDDEN; k0 += 32) {
    for (int i = 0; i < 8; ++i) {
      int idx = tid + i * 256;
      int r = idx >> 5, kk = idx & 31;
      Xs[r][kk] = X[(size_t)(row0 + r) * HIDDEN + k0 + kk];
      Bs[r][kk] = B[(size_t)r * HIDDEN + k0 + kk];
    }
    __syncthreads();
    for (int kk = 0; kk < 32; ++kk) {
      float xv[4], bv[4];
      #pragma unroll
      for (int i = 0; i < 4; ++i) xv[i] = Xs[ty * 4 + i][kk];
      #pragma unroll
      for (int j = 0; j < 4; ++j) bv[j] = Bs[tx + 16 * j][kk];
      #pragma unroll
      for (int i = 0; i < 4; ++i)
        #pragma unroll
        for (int j = 0; j < 4; ++j) acc[i][j] += xv[i] * bv[j];
    }
    __syncthreads();
  }
  for (int i = 0; i < 4; ++i)
    for (int j = 0; j < 4; ++j)
      R[(size_t)(row0 + ty * 4 + i) * HARM + tx + 16 * j] = acc[i][j];
}

// ------------------------------------ P[M x 2048] = R[M x 64] * W[2048 x 64]^T (K=64)
__global__ __launch_bounds__(256) void proj_kernel(
    const float* __restrict__ R, const float* __restrict__ W,
    float* __restrict__ P) {
  const int row0 = blockIdx.x * 32;
  const int col0 = blockIdx.y * 128;
  __shared__ float Rs[32][65];
  __shared__ float Ws[128][65];
  const int tid = threadIdx.x;
  for (int i = 0; i < 8; ++i) {
    int idx = tid + i * 256;
    int r = idx >> 6, kk = idx & 63;
    Rs[r][kk] = R[(size_t)(row0 + r) * HARM + kk];
  }
  for (int i = 0; i < 32; ++i) {
    int idx = tid + i * 256;
    int c = idx >> 6, kk = idx & 63;
    Ws[c][kk] = W[(size_t)(col0 + c) * HARM + kk];
  }
  __syncthreads();
  const int ty = tid >> 5, tx = tid & 31;
  float acc[4][4] = {};
  for (int kk = 0; kk < 64; ++kk) {
    float rv[4], wv[4];
    #pragma unroll
    for (int i = 0; i < 4; ++i) rv[i] = Rs[ty * 4 + i][kk];
    #pragma unroll
    for (int j = 0; j < 4; ++j) wv[j] = Ws[tx + 32 * j][kk];
    #pragma unroll
    for (int i = 0; i < 4; ++i)
      #pragma unroll
      for (int j = 0; j < 4; ++j) acc[i][j] += rv[i] * wv[j];
  }
  for (int i = 0; i < 4; ++i)
    for (int j = 0; j < 4; ++j)
      P[(size_t)(row0 + ty * 4 + i) * HIDDEN + col0 + tx + 32 * j] = acc[i][j];
}

// bf16-output variant (Q/K/V projections feeding MFMA attention)
__global__ __launch_bounds__(256) void proj_bf16_kernel(
    const float* __restrict__ R, const float* __restrict__ W,
    __hip_bfloat16* __restrict__ P) {
  const int row0 = blockIdx.x * 32;
  const int col0 = blockIdx.y * 128;
  __shared__ float Rs[32][65];
  __shared__ float Ws[128][65];
  const int tid = threadIdx.x;
  for (int i = 0; i < 8; ++i) {
    int idx = tid + i * 256;
    int r = idx >> 6, kk = idx & 63;
    Rs[r][kk] = R[(size_t)(row0 + r) * HARM + kk];
  }
  for (int i = 0; i < 32; ++i) {
    int idx = tid + i * 256;
    int c = idx >> 6, kk = idx & 63;
    Ws[c][kk] = W[(size_t)(col0 + c) * HARM + kk];
  }
  __syncthreads();
  const int ty = tid >> 5, tx = tid & 31;
  float acc[4][4] = {};
  for (int kk = 0; kk < 64; ++kk) {
    float rv[4], wv[4];
    #pragma unroll
    for (int i = 0; i < 4; ++i) rv[i] = Rs[ty * 4 + i][kk];
    #pragma unroll
    for (int j = 0; j < 4; ++j) wv[j] = Ws[tx + 32 * j][kk];
    #pragma unroll
    for (int i = 0; i < 4; ++i)
      #pragma unroll
      for (int j = 0; j < 4; ++j) acc[i][j] += rv[i] * wv[j];
  }
  for (int i = 0; i < 4; ++i)
    for (int j = 0; j < 4; ++j)
      P[(size_t)(row0 + ty * 4 + i) * HIDDEN + col0 + tx + 32 * j] =
          __float2bfloat16(acc[i][j]);
}

// -------------------------------------- per-batch 2048x2048 bf16 transpose (V -> V^T)
__global__ __launch_bounds__(256) void transpose_v(
    const ushort* __restrict__ S, ushort* __restrict__ D) {
  const int b = blockIdx.z;
  const int r0 = blockIdx.y * 32, c0 = blockIdx.x * 32;
  __shared__ ushort tile[32][33];
  const int t = threadIdx.x;
  const int r = t >> 3, cs = (t & 7) * 4;
  const ushort* Sb = S + (size_t)b * SEQ * HIDDEN;
  ushort* Db = D + (size_t)b * SEQ * HIDDEN;
  ushort4 v = *(const ushort4*)&Sb[(size_t)(r0 + r) * HIDDEN + c0 + cs];
  tile[r][cs] = v.x; tile[r][cs + 1] = v.y; tile[r][cs + 2] = v.z; tile[r][cs + 3] = v.w;
  __syncthreads();
  ushort4 o;
  o.x = tile[cs + 0][r]; o.y = tile[cs + 1][r];
  o.z = tile[cs + 2][r]; o.w = tile[cs + 3][r];
  *(ushort4*)&Db[(size_t)(c0 + r) * SEQ + r0 + cs] = o;
}

// ----------------------------------------------------------- MFMA flash attention
// Same structure as round 2, but ALL per-lane state in statically-indexed
// ext_vector registers (no runtime-selected pointers -> no SROA failure/scratch).
#define BQ 128
#define BK 64
#define KSTR 136   // Qs/Ks row stride (ushorts)
#define VSTR 72    // Vs row stride (ushorts)

__device__ inline unsigned pkbf(float a, float b) {
  __hip_bfloat162 h2 = __float22bfloat162_rn(make_float2(a, b));
  union { __hip_bfloat162 h; unsigned u; } cv; cv.h = h2; return cv.u;
}

__global__ __launch_bounds__(256, 2) void attn_mfma(
    const ushort* __restrict__ Qg, const ushort* __restrict__ Kg,
    const ushort* __restrict__ Vt, float* __restrict__ O) {
  __shared__ __align__(16) union SM {
    ushort q[BQ][KSTR];
    struct { ushort k[BK][KSTR]; ushort v[HDIM][VSTR]; } kv;
  } sm;
  const int t = threadIdx.x;
  const int bh = blockIdx.x & 31;
  const int qt = blockIdx.x >> 5;
  const int b = bh >> 4, h = bh & 15;
  const int q0 = qt * BQ;
  const int lane = t & 63;
  const int w = t >> 6;
  const int l31 = lane & 31;
  const int hh = lane >> 5;
  const bool hi = (hh != 0);
  const float SC2 = 0.08838834764831845f * 1.4426950408889634f;  // scale * log2(e)

  // ---- stage Q tile and pull B-fragments into registers
  {
    const size_t gbase = ((size_t)(b * SEQ + q0)) * HIDDEN + h * HDIM;
    for (int p = 0; p < 8; ++p) {
      int row = p * 16 + (t >> 4);
      int d0 = (t & 15) * 8;
      uint4 v = *(const uint4*)&Qg[gbase + (size_t)row * HIDDEN + d0];
      *(uint4*)&sm.q[row][d0] = v;
    }
  }
  __syncthreads();
  bf16x8 Qf[8];
  {
    const int qrow = w * 32 + l31;
    #pragma unroll
    for (int ks = 0; ks < 8; ++ks)
      Qf[ks] = *(const bf16x8*)&sm.q[qrow][ks * 16 + 8 * hh];
  }
  __syncthreads();

  float mrow = -1e30f, lsum = 0.0f;
  f32x16 Ot[4];
  #pragma unroll
  for (int i = 0; i < 4; ++i)
    #pragma unroll
    for (int j = 0; j < 16; ++j) Ot[i][j] = 0.0f;

  for (int k0 = 0; k0 < SEQ; k0 += BK) {
    // ---- stage K chunk and V^T chunk
    {
      const size_t gb = ((size_t)(b * SEQ + k0)) * HIDDEN + h * HDIM;
      #pragma unroll
      for (int p = 0; p < 4; ++p) {
        int key = p * 16 + (t >> 4);
        int d0 = (t & 15) * 8;
        uint4 v = *(const uint4*)&Kg[gb + (size_t)key * HIDDEN + d0];
        *(uint4*)&sm.kv.k[key][d0] = v;
      }
      const size_t vb = ((size_t)(b * SEQ + h * HDIM)) * SEQ + k0;
      #pragma unroll
      for (int p = 0; p < 4; ++p) {
        int d = p * 32 + (t >> 3);
        int ks2 = (t & 7) * 8;
        uint4 v = *(const uint4*)&Vt[vb + (size_t)d * SEQ + ks2];
        *(uint4*)&sm.kv.v[d][ks2] = v;
      }
    }
    __syncthreads();

    // ---- S^T = K . Q^T   (two 32-key m-tiles)
    f32x16 C0, C1;
    #pragma unroll
    for (int j = 0; j < 16; ++j) { C0[j] = 0.0f; C1[j] = 0.0f; }
    #pragma unroll
    for (int ks = 0; ks < 8; ++ks) {
      bf16x8 a0 = *(const bf16x8*)&sm.kv.k[l31][ks * 16 + 8 * hh];
      bf16x8 a1 = *(const bf16x8*)&sm.kv.k[32 + l31][ks * 16 + 8 * hh];
      C0 = __builtin_amdgcn_mfma_f32_32x32x16_bf16(a0, Qf[ks], C0, 0, 0, 0);
      C1 = __builtin_amdgcn_mfma_f32_32x32x16_bf16(a1, Qf[ks], C1, 0, 0, 0);
    }

    // ---- online softmax, fully static indexing; exp'd P overwrites C0/C1
    float mxr = -1e30f;
    #pragma unroll
    for (int j = 0; j < 16; ++j) mxr = fmaxf(mxr, fmaxf(C0[j], C1[j]));
    mxr = fmaxf(mxr, __shfl_xor(mxr, 32));
    const float mnew = fmaxf(mrow, mxr * SC2);
    const float alpha = exp2f(mrow - mnew);
    float ssum = 0.0f;
    #pragma unroll
    for (int j = 0; j < 16; ++j) {
      float e0 = exp2f(fmaf(C0[j], SC2, -mnew));
      float e1 = exp2f(fmaf(C1[j], SC2, -mnew));
      C0[j] = e0; C1[j] = e1;
      ssum += e0 + e1;
    }
    ssum += __shfl_xor(ssum, 32);
    lsum = lsum * alpha + ssum;
    mrow = mnew;
    #pragma unroll
    for (int i = 0; i < 4; ++i)
      #pragma unroll
      for (int j = 0; j < 16; ++j) Ot[i][j] *= alpha;

    // ---- O^T += V^T . P^T   (4 k-steps of 16 keys)
    // tile u = st>>1 (compile-time); element base = 8*(st&1) + 4*hh (one hh bit).
    #pragma unroll
    for (int st = 0; st < 4; ++st) {
      const int eb = 8 * (st & 1);
      float o0, o1, o2, o3, g0, g1, g2, g3;
      if (st < 2) {
        o0 = hi ? C0[eb + 4] : C0[eb + 0]; o1 = hi ? C0[eb + 5] : C0[eb + 1];
        o2 = hi ? C0[eb + 6] : C0[eb + 2]; o3 = hi ? C0[eb + 7] : C0[eb + 3];
        g0 = hi ? C0[eb + 0] : C0[eb + 4]; g1 = hi ? C0[eb + 1] : C0[eb + 5];
        g2 = hi ? C0[eb + 2] : C0[eb + 6]; g3 = hi ? C0[eb + 3] : C0[eb + 7];
      } else {
        o0 = hi ? C1[eb + 4] : C1[eb + 0]; o1 = hi ? C1[eb + 5] : C1[eb + 1];
        o2 = hi ? C1[eb + 6] : C1[eb + 2]; o3 = hi ? C1[eb + 7] : C1[eb + 3];
        g0 = hi ? C1[eb + 0] : C1[eb + 4]; g1 = hi ? C1[eb + 1] : C1[eb + 5];
        g2 = hi ? C1[eb + 2] : C1[eb + 6]; g3 = hi ? C1[eb + 3] : C1[eb + 7];
      }
      unsigned so0 = pkbf(o0, o1), so1 = pkbf(o2, o3);
      unsigned sp0 = pkbf(g0, g1), sp1 = pkbf(g2, g3);
      unsigned r0 = (unsigned)__shfl_xor((int)sp0, 32);
      unsigned r1 = (unsigned)__shfl_xor((int)sp1, 32);
      union { unsigned u[4]; bf16x8 v; } cv;
      cv.u[0] = hi ? r0 : so0;
      cv.u[1] = hi ? r1 : so1;
      cv.u[2] = hi ? so0 : r0;
      cv.u[3] = hi ? so1 : r1;
      #pragma unroll
      for (int mt = 0; mt < 4; ++mt) {
        bf16x8 a2 = *(const bf16x8*)&sm.kv.v[mt * 32 + l31][st * 16 + 8 * hh];
        Ot[mt] = __builtin_amdgcn_mfma_f32_32x32x16_bf16(a2, cv.v, Ot[mt], 0, 0, 0);
      }
    }
    __syncthreads();
  }

  // ---- epilogue
  const float inv = 1.0f / lsum;
  const int qrow = q0 + w * 32 + l31;
  float* ob = O + ((size_t)(b * SEQ + qrow)) * HIDDEN + h * HDIM;
  #pragma unroll
  for (int mt = 0; mt < 4; ++mt)
    #pragma unroll
    for (int g = 0; g < 4; ++g) {
      float4 vv = make_float4(Ot[mt][4 * g + 0] * inv, Ot[mt][4 * g + 1] * inv,
                              Ot[mt][4 * g + 2] * inv, Ot[mt][4 * g + 3] * inv);
      *(float4*)&ob[mt * 32 + 8 * g + 4 * hh] = vv;
    }
}

// -------------------------------------------------------------------------- launcher
extern "C" void kernel_launch(void* const* d_in, const int* in_sizes, int n_in,
                              void* d_out, int out_size, void* d_ws, size_t ws_size,
                              hipStream_t stream) {
  (void)in_sizes; (void)n_in; (void)out_size; (void)ws_size;
  const float* X       = (const float*)d_in[0];
  const float* basis_q = (const float*)d_in[1];
  const float* phase_q = (const float*)d_in[2];
  const float* amp_q   = (const float*)d_in[3];
  const float* basis_k = (const float*)d_in[4];
  const float* phase_k = (const float*)d_in[5];
  const float* amp_k   = (const float*)d_in[6];
  const float* basis_v = (const float*)d_in[7];
  const float* phase_v = (const float*)d_in[8];
  const float* amp_v   = (const float*)d_in[9];
  const float* basis_o = (const float*)d_in[10];
  const float* phase_o = (const float*)d_in[11];
  const float* amp_o   = (const float*)d_in[12];

  const size_t WN = (size_t)HIDDEN * HARM;
  const size_t RN = (size_t)ROWS * HARM;
  const size_t PN = (size_t)ROWS * HIDDEN;

  char* p = (char*)d_ws;
  float* Wq = (float*)p; p += WN * 4;
  float* Wk = (float*)p; p += WN * 4;
  float* Wv = (float*)p; p += WN * 4;
  float* Wo = (float*)p; p += WN * 4;
  float* Rq = (float*)p; p += RN * 4;
  float* Rk = (float*)p; p += RN * 4;
  float* Rv = (float*)p; p += RN * 4;
  __hip_bfloat16* Qb = (__hip_bfloat16*)p; p += PN * 2;
  __hip_bfloat16* Kb = (__hip_bfloat16*)p; p += PN * 2;
  __hip_bfloat16* Vb = (__hip_bfloat16*)p; p += PN * 2;
  __hip_bfloat16* VtB = (__hip_bfloat16*)p; p += PN * 2;
  float* AO = (float*)p; p += PN * 4;
  float* out = (float*)d_out;

  w_kernel<<<(int)((4 * WN + 255) / 256), 256, 0, stream>>>(
      phase_q, amp_q, phase_k, amp_k, phase_v, amp_v, phase_o, amp_o, Wq);

  resonance_kernel<<<ROWS / 64, 256, 0, stream>>>(X, basis_q, Rq);
  resonance_kernel<<<ROWS / 64, 256, 0, stream>>>(X, basis_k, Rk);
  resonance_kernel<<<ROWS / 64, 256, 0, stream>>>(X, basis_v, Rv);

  dim3 pg(ROWS / 32, HIDDEN / 128);
  proj_bf16_kernel<<<pg, 256, 0, stream>>>(Rq, Wq, Qb);
  proj_bf16_kernel<<<pg, 256, 0, stream>>>(Rk, Wk, Kb);
  proj_bf16_kernel<<<pg, 256, 0, stream>>>(Rv, Wv, Vb);

  dim3 tg(HIDDEN / 32, SEQ / 32, BATCH);
  transpose_v<<<tg, 256, 0, stream>>>((const ushort*)Vb, (ushort*)VtB);

  attn_mfma<<<dim3((SEQ / BQ) * 32), 256, 0, stream>>>(
      (const ushort*)Qb, (const ushort*)Kb, (const ushort*)VtB, AO);

  resonance_kernel<<<ROWS / 64, 256, 0, stream>>>(AO, basis_o, Rq);
  proj_kernel<<<pg, 256, 0, stream>>>(Rq, Wo, out);
}

// Round 4
// 409.862 us; speedup vs baseline: 7.2878x; 2.0566x over previous
//
#include <hip/hip_runtime.h>
#include <hip/hip_bf16.h>
#include <math.h>

#define HIDDEN 2048
#define HARM   64
#define NHEADS 16
#define HDIM   128
#define SEQ    2048
#define BATCH  2
#define ROWS   (BATCH*SEQ)   // 4096
#define RN     (ROWS*HARM)   // 262144 (one K-chunk partial plane)

using bf16x8 = __attribute__((ext_vector_type(8))) short;
using f32x16 = __attribute__((ext_vector_type(16))) float;

// ------------------------------------------- WT[h][o] = amp[o][h] * cos(phase[o][h])
// grid 2048 x 256 covers 4*2048*64 elems exactly. Scattered 4B writes are absorbed
// by L2 (0.5 MB per matrix stays resident).
__global__ __launch_bounds__(256) void wt_kernel(
    const float* __restrict__ pq, const float* __restrict__ aq,
    const float* __restrict__ pk, const float* __restrict__ ak,
    const float* __restrict__ pv, const float* __restrict__ av,
    const float* __restrict__ po, const float* __restrict__ ao,
    float* __restrict__ Tq, float* __restrict__ Tk,
    float* __restrict__ Tv, float* __restrict__ To) {
  int i = blockIdx.x * 256 + threadIdx.x;
  const int N = HIDDEN * HARM;
  int set = i / N, j = i - set * N;
  int o = j >> 6, h = j & 63;
  const float* p = (set == 0) ? pq : (set == 1) ? pk : (set == 2) ? pv : po;
  const float* a = (set == 0) ? aq : (set == 1) ? ak : (set == 2) ? av : ao;
  float* T = (set == 0) ? Tq : (set == 1) ? Tk : (set == 2) ? Tv : To;
  T[h * HIDDEN + o] = a[j] * cosf(p[j]);
}

// --------------------------- basis[64][2048] -> BT[2048][64]  (grid 64 x 2 x 4)
__global__ __launch_bounds__(256) void transpose_basis(
    const float* __restrict__ b0, const float* __restrict__ b1,
    const float* __restrict__ b2, const float* __restrict__ b3,
    float* __restrict__ t0, float* __restrict__ t1,
    float* __restrict__ t2, float* __restrict__ t3) {
  const int z = blockIdx.z;
  const float* S = (z == 0) ? b0 : (z == 1) ? b1 : (z == 2) ? b2 : b3;
  float* D = (z == 0) ? t0 : (z == 1) ? t1 : (z == 2) ? t2 : t3;
  const int c0 = blockIdx.x * 32, r0 = blockIdx.y * 32;
  __shared__ float tile[32][33];
  const int t = threadIdx.x;
  const int r = t >> 3, cs = (t & 7) * 4;
  float4 v = *(const float4*)&S[(size_t)(r0 + r) * HIDDEN + c0 + cs];
  tile[r][cs] = v.x; tile[r][cs + 1] = v.y; tile[r][cs + 2] = v.z; tile[r][cs + 3] = v.w;
  __syncthreads();
  float4 o;
  o.x = tile[cs + 0][r]; o.y = tile[cs + 1][r];
  o.z = tile[cs + 2][r]; o.w = tile[cs + 3][r];
  *(float4*)&D[(size_t)(c0 + r) * HARM + r0 + cs] = o;
}

// --------------- split-K resonance: Rp[kc][M][64] += X[M][Kc] * BT[Kc][64]
// grid (64 M-tiles, 4 K-chunks of 512, nb bases). K-major LDS tiles; inner loop is
// two ds_read_b128 + 16 FMA per kk.
__global__ __launch_bounds__(256) void resonance_split(
    const float* __restrict__ X,
    const float* __restrict__ B0, const float* __restrict__ B1,
    const float* __restrict__ B2,
    float* __restrict__ R0, float* __restrict__ R1, float* __restrict__ R2) {
  const int z = blockIdx.z;
  const float* BT = (z == 0) ? B0 : (z == 1) ? B1 : B2;
  float* Rp = (z == 0) ? R0 : (z == 1) ? R1 : R2;
  const int row0 = blockIdx.x * 64;
  const int kc = blockIdx.y;
  __shared__ float Xt[32][68];   // [kk][row]
  __shared__ float Bt[32][68];   // [kk][col]
  const int tid = threadIdx.x;
  const int ty = tid >> 4, tx = tid & 15;   // 16x16 thread grid, 4x4 micro-tile
  float acc[4][4] = {};
  const int kbase = kc * 512;
  for (int k0 = kbase; k0 < kbase + 512; k0 += 32) {
    #pragma unroll
    for (int i = 0; i < 8; ++i) {
      int idx = tid + i * 256;
      int r = idx >> 5, kk = idx & 31;           // coalesced global (kk fastest)
      Xt[kk][r] = X[(size_t)(row0 + r) * HIDDEN + k0 + kk];
      int rb = idx & 63, kb = idx >> 6;          // BT: coalesced, LDS write contiguous
      Bt[kb][rb] = BT[(size_t)(k0 + kb) * HARM + rb];
    }
    __syncthreads();
    #pragma unroll
    for (int kk = 0; kk < 32; ++kk) {
      float4 xv = *(const float4*)&Xt[kk][ty * 4];
      float4 bv = *(const float4*)&Bt[kk][tx * 4];
      acc[0][0] += xv.x * bv.x; acc[0][1] += xv.x * bv.y; acc[0][2] += xv.x * bv.z; acc[0][3] += xv.x * bv.w;
      acc[1][0] += xv.y * bv.x; acc[1][1] += xv.y * bv.y; acc[1][2] += xv.y * bv.z; acc[1][3] += xv.y * bv.w;
      acc[2][0] += xv.z * bv.x; acc[2][1] += xv.z * bv.y; acc[2][2] += xv.z * bv.z; acc[2][3] += xv.z * bv.w;
      acc[3][0] += xv.w * bv.x; acc[3][1] += xv.w * bv.y; acc[3][2] += xv.w * bv.z; acc[3][3] += xv.w * bv.w;
    }
    __syncthreads();
  }
  #pragma unroll
  for (int i = 0; i < 4; ++i) {
    float4 v = make_float4(acc[i][0], acc[i][1], acc[i][2], acc[i][3]);
    *(float4*)&Rp[(size_t)(kc * ROWS + row0 + ty * 4 + i) * HARM + tx * 4] = v;
  }
}

// --------------- projection: P[M][2048] = (sum_kc Rp[kc]) [M][64] * WT[64][2048]
// bf16-output fused QKV variant, grid (128, 16, 3). K-major LDS, b128 reads.
__global__ __launch_bounds__(256) void proj_bf16_f(
    const float* __restrict__ Rp0, const float* __restrict__ Rp1,
    const float* __restrict__ Rp2,
    const float* __restrict__ T0, const float* __restrict__ T1,
    const float* __restrict__ T2,
    ushort* __restrict__ P0, ushort* __restrict__ P1, ushort* __restrict__ P2) {
  const int z = blockIdx.z;
  const float* Rp = (z == 0) ? Rp0 : (z == 1) ? Rp1 : Rp2;
  const float* WT = (z == 0) ? T0 : (z == 1) ? T1 : T2;
  ushort* P = (z == 0) ? P0 : (z == 1) ? P1 : P2;
  const int row0 = blockIdx.x * 32;
  const int col0 = blockIdx.y * 128;
  __shared__ float Rt[64][36];    // [kk][row]
  __shared__ float Wt[64][132];   // [kk][col]
  const int tid = threadIdx.x;
  #pragma unroll
  for (int i = 0; i < 8; ++i) {   // Rt staging with fused 4-partial reduce
    int idx = tid + i * 256;
    int r = idx >> 6, kk = idx & 63;
    size_t o = (size_t)(row0 + r) * HARM + kk;
    Rt[kk][r] = Rp[o] + Rp[RN + o] + Rp[2 * (size_t)RN + o] + Rp[3 * (size_t)RN + o];
  }
  #pragma unroll
  for (int i = 0; i < 32; ++i) {  // Wt staging: coalesced global, contiguous LDS
    int idx = tid + i * 256;
    int c = idx & 127, kk = idx >> 7;
    Wt[kk][c] = WT[(size_t)kk * HIDDEN + col0 + c];
  }
  __syncthreads();
  const int ty = tid >> 5, tx = tid & 31;   // rows ty*4, cols tx*4
  float acc[4][4] = {};
  #pragma unroll
  for (int kk = 0; kk < 64; ++kk) {
    float4 rv = *(const float4*)&Rt[kk][ty * 4];
    float4 wv = *(const float4*)&Wt[kk][tx * 4];
    acc[0][0] += rv.x * wv.x; acc[0][1] += rv.x * wv.y; acc[0][2] += rv.x * wv.z; acc[0][3] += rv.x * wv.w;
    acc[1][0] += rv.y * wv.x; acc[1][1] += rv.y * wv.y; acc[1][2] += rv.y * wv.z; acc[1][3] += rv.y * wv.w;
    acc[2][0] += rv.z * wv.x; acc[2][1] += rv.z * wv.y; acc[2][2] += rv.z * wv.z; acc[2][3] += rv.z * wv.w;
    acc[3][0] += rv.w * wv.x; acc[3][1] += rv.w * wv.y; acc[3][2] += rv.w * wv.z; acc[3][3] += rv.w * wv.w;
  }
  #pragma unroll
  for (int i = 0; i < 4; ++i) {
    union { ushort4 s; __hip_bfloat16 b[4]; } cv;
    cv.b[0] = __float2bfloat16(acc[i][0]); cv.b[1] = __float2bfloat16(acc[i][1]);
    cv.b[2] = __float2bfloat16(acc[i][2]); cv.b[3] = __float2bfloat16(acc[i][3]);
    *(ushort4*)&P[(size_t)(row0 + ty * 4 + i) * HIDDEN + col0 + tx * 4] = cv.s;
  }
}

// fp32-output single variant (final o-projection), grid (128, 16)
__global__ __launch_bounds__(256) void proj_f32(
    const float* __restrict__ Rp, const float* __restrict__ WT,
    float* __restrict__ P) {
  const int row0 = blockIdx.x * 32;
  const int col0 = blockIdx.y * 128;
  __shared__ float Rt[64][36];
  __shared__ float Wt[64][132];
  const int tid = threadIdx.x;
  #pragma unroll
  for (int i = 0; i < 8; ++i) {
    int idx = tid + i * 256;
    int r = idx >> 6, kk = idx & 63;
    size_t o = (size_t)(row0 + r) * HARM + kk;
    Rt[kk][r] = Rp[o] + Rp[RN + o] + Rp[2 * (size_t)RN + o] + Rp[3 * (size_t)RN + o];
  }
  #pragma unroll
  for (int i = 0; i < 32; ++i) {
    int idx = tid + i * 256;
    int c = idx & 127, kk = idx >> 7;
    Wt[kk][c] = WT[(size_t)kk * HIDDEN + col0 + c];
  }
  __syncthreads();
  const int ty = tid >> 5, tx = tid & 31;
  float acc[4][4] = {};
  #pragma unroll
  for (int kk = 0; kk < 64; ++kk) {
    float4 rv = *(const float4*)&Rt[kk][ty * 4];
    float4 wv = *(const float4*)&Wt[kk][tx * 4];
    acc[0][0] += rv.x * wv.x; acc[0][1] += rv.x * wv.y; acc[0][2] += rv.x * wv.z; acc[0][3] += rv.x * wv.w;
    acc[1][0] += rv.y * wv.x; acc[1][1] += rv.y * wv.y; acc[1][2] += rv.y * wv.z; acc[1][3] += rv.y * wv.w;
    acc[2][0] += rv.z * wv.x; acc[2][1] += rv.z * wv.y; acc[2][2] += rv.z * wv.z; acc[2][3] += rv.z * wv.w;
    acc[3][0] += rv.w * wv.x; acc[3][1] += rv.w * wv.y; acc[3][2] += rv.w * wv.z; acc[3][3] += rv.w * wv.w;
  }
  #pragma unroll
  for (int i = 0; i < 4; ++i) {
    float4 v = make_float4(acc[i][0], acc[i][1], acc[i][2], acc[i][3]);
    *(float4*)&P[(size_t)(row0 + ty * 4 + i) * HIDDEN + col0 + tx * 4] = v;
  }
}

// -------------------------------------- per-batch 2048x2048 bf16 transpose (V -> V^T)
__global__ __launch_bounds__(256) void transpose_v(
    const ushort* __restrict__ S, ushort* __restrict__ D) {
  const int b = blockIdx.z;
  const int r0 = blockIdx.y * 32, c0 = blockIdx.x * 32;
  __shared__ ushort tile[32][33];
  const int t = threadIdx.x;
  const int r = t >> 3, cs = (t & 7) * 4;
  const ushort* Sb = S + (size_t)b * SEQ * HIDDEN;
  ushort* Db = D + (size_t)b * SEQ * HIDDEN;
  ushort4 v = *(const ushort4*)&Sb[(size_t)(r0 + r) * HIDDEN + c0 + cs];
  tile[r][cs] = v.x; tile[r][cs + 1] = v.y; tile[r][cs + 2] = v.z; tile[r][cs + 3] = v.w;
  __syncthreads();
  ushort4 o;
  o.x = tile[cs + 0][r]; o.y = tile[cs + 1][r];
  o.z = tile[cs + 2][r]; o.w = tile[cs + 3][r];
  *(ushort4*)&Db[(size_t)(c0 + r) * SEQ + r0 + cs] = o;
}

// ----------------------------------------------------------- MFMA flash attention
#define BQ 128
#define BK 64
#define KSTR 136
#define VSTR 72

__device__ inline unsigned pkbf(float a, float b) {
  __hip_bfloat162 h2 = __float22bfloat162_rn(make_float2(a, b));
  union { __hip_bfloat162 h; unsigned u; } cv; cv.h = h2; return cv.u;
}

__global__ __launch_bounds__(256, 2) void attn_mfma(
    const ushort* __restrict__ Qg, const ushort* __restrict__ Kg,
    const ushort* __restrict__ Vt, float* __restrict__ O) {
  __shared__ __align__(16) union SM {
    ushort q[BQ][KSTR];
    struct { ushort k[BK][KSTR]; ushort v[HDIM][VSTR]; } kv;
  } sm;
  const int t = threadIdx.x;
  const int bh = blockIdx.x & 31;
  const int qt = blockIdx.x >> 5;
  const int b = bh >> 4, h = bh & 15;
  const int q0 = qt * BQ;
  const int lane = t & 63;
  const int w = t >> 6;
  const int l31 = lane & 31;
  const int hh = lane >> 5;
  const bool hi = (hh != 0);
  const float SC2 = 0.08838834764831845f * 1.4426950408889634f;

  {
    const size_t gbase = ((size_t)(b * SEQ + q0)) * HIDDEN + h * HDIM;
    for (int p = 0; p < 8; ++p) {
      int row = p * 16 + (t >> 4);
      int d0 = (t & 15) * 8;
      uint4 v = *(const uint4*)&Qg[gbase + (size_t)row * HIDDEN + d0];
      *(uint4*)&sm.q[row][d0] = v;
    }
  }
  __syncthreads();
  bf16x8 Qf[8];
  {
    const int qrow = w * 32 + l31;
    #pragma unroll
    for (int ks = 0; ks < 8; ++ks)
      Qf[ks] = *(const bf16x8*)&sm.q[qrow][ks * 16 + 8 * hh];
  }
  __syncthreads();

  float mrow = -1e30f, lsum = 0.0f;
  f32x16 Ot[4];
  #pragma unroll
  for (int i = 0; i < 4; ++i)
    #pragma unroll
    for (int j = 0; j < 16; ++j) Ot[i][j] = 0.0f;

  for (int k0 = 0; k0 < SEQ; k0 += BK) {
    {
      const size_t gb = ((size_t)(b * SEQ + k0)) * HIDDEN + h * HDIM;
      #pragma unroll
      for (int p = 0; p < 4; ++p) {
        int key = p * 16 + (t >> 4);
        int d0 = (t & 15) * 8;
        uint4 v = *(const uint4*)&Kg[gb + (size_t)key * HIDDEN + d0];
        *(uint4*)&sm.kv.k[key][d0] = v;
      }
      const size_t vb = ((size_t)(b * SEQ + h * HDIM)) * SEQ + k0;
      #pragma unroll
      for (int p = 0; p < 4; ++p) {
        int d = p * 32 + (t >> 3);
        int ks2 = (t & 7) * 8;
        uint4 v = *(const uint4*)&Vt[vb + (size_t)d * SEQ + ks2];
        *(uint4*)&sm.kv.v[d][ks2] = v;
      }
    }
    __syncthreads();

    f32x16 C0, C1;
    #pragma unroll
    for (int j = 0; j < 16; ++j) { C0[j] = 0.0f; C1[j] = 0.0f; }
    #pragma unroll
    for (int ks = 0; ks < 8; ++ks) {
      bf16x8 a0 = *(const bf16x8*)&sm.kv.k[l31][ks * 16 + 8 * hh];
      bf16x8 a1 = *(const bf16x8*)&sm.kv.k[32 + l31][ks * 16 + 8 * hh];
      C0 = __builtin_amdgcn_mfma_f32_32x32x16_bf16(a0, Qf[ks], C0, 0, 0, 0);
      C1 = __builtin_amdgcn_mfma_f32_32x32x16_bf16(a1, Qf[ks], C1, 0, 0, 0);
    }

    float mxr = -1e30f;
    #pragma unroll
    for (int j = 0; j < 16; ++j) mxr = fmaxf(mxr, fmaxf(C0[j], C1[j]));
    mxr = fmaxf(mxr, __shfl_xor(mxr, 32));
    const float mnew = fmaxf(mrow, mxr * SC2);
    const float alpha = exp2f(mrow - mnew);
    float ssum = 0.0f;
    #pragma unroll
    for (int j = 0; j < 16; ++j) {
      float e0 = exp2f(fmaf(C0[j], SC2, -mnew));
      float e1 = exp2f(fmaf(C1[j], SC2, -mnew));
      C0[j] = e0; C1[j] = e1;
      ssum += e0 + e1;
    }
    ssum += __shfl_xor(ssum, 32);
    lsum = lsum * alpha + ssum;
    mrow = mnew;
    #pragma unroll
    for (int i = 0; i < 4; ++i)
      #pragma unroll
      for (int j = 0; j < 16; ++j) Ot[i][j] *= alpha;

    #pragma unroll
    for (int st = 0; st < 4; ++st) {
      const int eb = 8 * (st & 1);
      float o0, o1, o2, o3, g0, g1, g2, g3;
      if (st < 2) {
        o0 = hi ? C0[eb + 4] : C0[eb + 0]; o1 = hi ? C0[eb + 5] : C0[eb + 1];
        o2 = hi ? C0[eb + 6] : C0[eb + 2]; o3 = hi ? C0[eb + 7] : C0[eb + 3];
        g0 = hi ? C0[eb + 0] : C0[eb + 4]; g1 = hi ? C0[eb + 1] : C0[eb + 5];
        g2 = hi ? C0[eb + 2] : C0[eb + 6]; g3 = hi ? C0[eb + 3] : C0[eb + 7];
      } else {
        o0 = hi ? C1[eb + 4] : C1[eb + 0]; o1 = hi ? C1[eb + 5] : C1[eb + 1];
        o2 = hi ? C1[eb + 6] : C1[eb + 2]; o3 = hi ? C1[eb + 7] : C1[eb + 3];
        g0 = hi ? C1[eb + 0] : C1[eb + 4]; g1 = hi ? C1[eb + 1] : C1[eb + 5];
        g2 = hi ? C1[eb + 2] : C1[eb + 6]; g3 = hi ? C1[eb + 3] : C1[eb + 7];
      }
      unsigned so0 = pkbf(o0, o1), so1 = pkbf(o2, o3);
      unsigned sp0 = pkbf(g0, g1), sp1 = pkbf(g2, g3);
      unsigned r0 = (unsigned)__shfl_xor((int)sp0, 32);
      unsigned r1 = (unsigned)__shfl_xor((int)sp1, 32);
      union { unsigned u[4]; bf16x8 v; } cv;
      cv.u[0] = hi ? r0 : so0;
      cv.u[1] = hi ? r1 : so1;
      cv.u[2] = hi ? so0 : r0;
      cv.u[3] = hi ? so1 : r1;
      #pragma unroll
      for (int mt = 0; mt < 4; ++mt) {
        bf16x8 a2 = *(const bf16x8*)&sm.kv.v[mt * 32 + l31][st * 16 + 8 * hh];
        Ot[mt] = __builtin_amdgcn_mfma_f32_32x32x16_bf16(a2, cv.v, Ot[mt], 0, 0, 0);
      }
    }
    __syncthreads();
  }

  const float inv = 1.0f / lsum;
  const int qrow = q0 + w * 32 + l31;
  float* ob = O + ((size_t)(b * SEQ + qrow)) * HIDDEN + h * HDIM;
  #pragma unroll
  for (int mt = 0; mt < 4; ++mt)
    #pragma unroll
    for (int g = 0; g < 4; ++g) {
      float4 vv = make_float4(Ot[mt][4 * g + 0] * inv, Ot[mt][4 * g + 1] * inv,
                              Ot[mt][4 * g + 2] * inv, Ot[mt][4 * g + 3] * inv);
      *(float4*)&ob[mt * 32 + 8 * g + 4 * hh] = vv;
    }
}

// -------------------------------------------------------------------------- launcher
extern "C" void kernel_launch(void* const* d_in, const int* in_sizes, int n_in,
                              void* d_out, int out_size, void* d_ws, size_t ws_size,
                              hipStream_t stream) {
  (void)in_sizes; (void)n_in; (void)out_size; (void)ws_size;
  const float* X       = (const float*)d_in[0];
  const float* basis_q = (const float*)d_in[1];
  const float* phase_q = (const float*)d_in[2];
  const float* amp_q   = (const float*)d_in[3];
  const float* basis_k = (const float*)d_in[4];
  const float* phase_k = (const float*)d_in[5];
  const float* amp_k   = (const float*)d_in[6];
  const float* basis_v = (const float*)d_in[7];
  const float* phase_v = (const float*)d_in[8];
  const float* amp_v   = (const float*)d_in[9];
  const float* basis_o = (const float*)d_in[10];
  const float* phase_o = (const float*)d_in[11];
  const float* amp_o   = (const float*)d_in[12];

  const size_t WN = (size_t)HIDDEN * HARM;   // 131072
  const size_t PN = (size_t)ROWS * HIDDEN;   // 8388608

  char* p = (char*)d_ws;
  float* WTq = (float*)p; p += WN * 4;
  float* WTk = (float*)p; p += WN * 4;
  float* WTv = (float*)p; p += WN * 4;
  float* WTo = (float*)p; p += WN * 4;
  float* BTq = (float*)p; p += WN * 4;
  float* BTk = (float*)p; p += WN * 4;
  float* BTv = (float*)p; p += WN * 4;
  float* BTo = (float*)p; p += WN * 4;
  float* Rqp = (float*)p; p += (size_t)4 * RN * 4;
  float* Rkp = (float*)p; p += (size_t)4 * RN * 4;
  float* Rvp = (float*)p; p += (size_t)4 * RN * 4;
  float* Rop = (float*)p; p += (size_t)4 * RN * 4;
  __hip_bfloat16* Qb = (__hip_bfloat16*)p; p += PN * 2;
  __hip_bfloat16* Kb = (__hip_bfloat16*)p; p += PN * 2;
  __hip_bfloat16* Vb = (__hip_bfloat16*)p; p += PN * 2;
  __hip_bfloat16* VtB = (__hip_bfloat16*)p; p += PN * 2;
  float* AO = (float*)p; p += PN * 4;
  float* out = (float*)d_out;

  wt_kernel<<<2048, 256, 0, stream>>>(phase_q, amp_q, phase_k, amp_k,
                                      phase_v, amp_v, phase_o, amp_o,
                                      WTq, WTk, WTv, WTo);
  transpose_basis<<<dim3(64, 2, 4), 256, 0, stream>>>(
      basis_q, basis_k, basis_v, basis_o, BTq, BTk, BTv, BTo);

  resonance_split<<<dim3(64, 4, 3), 256, 0, stream>>>(
      X, BTq, BTk, BTv, Rqp, Rkp, Rvp);

  proj_bf16_f<<<dim3(128, 16, 3), 256, 0, stream>>>(
      Rqp, Rkp, Rvp, WTq, WTk, WTv,
      (ushort*)Qb, (ushort*)Kb, (ushort*)Vb);

  transpose_v<<<dim3(HIDDEN / 32, SEQ / 32, BATCH), 256, 0, stream>>>(
      (const ushort*)Vb, (ushort*)VtB);

  attn_mfma<<<dim3((SEQ / BQ) * 32), 256, 0, stream>>>(
      (const ushort*)Qb, (const ushort*)Kb, (const ushort*)VtB, AO);

  resonance_split<<<dim3(64, 4, 1), 256, 0, stream>>>(
      AO, BTo, BTo, BTo, Rop, Rop, Rop);

  proj_f32<<<dim3(128, 16), 256, 0, stream>>>(Rop, WTo, out);
}

// Round 5
// 402.471 us; speedup vs baseline: 7.4217x; 1.0184x over previous
//
#include <hip/hip_runtime.h>
#include <hip/hip_bf16.h>
#include <math.h>

#define HIDDEN 2048
#define HARM   64
#define NHEADS 16
#define HDIM   128
#define SEQ    2048
#define BATCH  2
#define ROWS   (BATCH*SEQ)   // 4096
#define RN     (ROWS*HARM)   // 262144 (one K-chunk partial plane)

using bf16x8 = __attribute__((ext_vector_type(8))) short;
using f32x16 = __attribute__((ext_vector_type(16))) float;

// ------------------------------------------- WT[h][o] = amp[o][h] * cos(phase[o][h])
__global__ __launch_bounds__(256) void wt_kernel(
    const float* __restrict__ pq, const float* __restrict__ aq,
    const float* __restrict__ pk, const float* __restrict__ ak,
    const float* __restrict__ pv, const float* __restrict__ av,
    const float* __restrict__ po, const float* __restrict__ ao,
    float* __restrict__ Tq, float* __restrict__ Tk,
    float* __restrict__ Tv, float* __restrict__ To) {
  int i = blockIdx.x * 256 + threadIdx.x;
  const int N = HIDDEN * HARM;
  int set = i / N, j = i - set * N;
  int o = j >> 6, h = j & 63;
  const float* p = (set == 0) ? pq : (set == 1) ? pk : (set == 2) ? pv : po;
  const float* a = (set == 0) ? aq : (set == 1) ? ak : (set == 2) ? av : ao;
  float* T = (set == 0) ? Tq : (set == 1) ? Tk : (set == 2) ? Tv : To;
  T[h * HIDDEN + o] = a[j] * cosf(p[j]);
}

// --------------------------- basis[64][2048] -> BT[2048][64]  (grid 64 x 2 x 4)
__global__ __launch_bounds__(256) void transpose_basis(
    const float* __restrict__ b0, const float* __restrict__ b1,
    const float* __restrict__ b2, const float* __restrict__ b3,
    float* __restrict__ t0, float* __restrict__ t1,
    float* __restrict__ t2, float* __restrict__ t3) {
  const int z = blockIdx.z;
  const float* S = (z == 0) ? b0 : (z == 1) ? b1 : (z == 2) ? b2 : b3;
  float* D = (z == 0) ? t0 : (z == 1) ? t1 : (z == 2) ? t2 : t3;
  const int c0 = blockIdx.x * 32, r0 = blockIdx.y * 32;
  __shared__ float tile[32][33];
  const int t = threadIdx.x;
  const int r = t >> 3, cs = (t & 7) * 4;
  float4 v = *(const float4*)&S[(size_t)(r0 + r) * HIDDEN + c0 + cs];
  tile[r][cs] = v.x; tile[r][cs + 1] = v.y; tile[r][cs + 2] = v.z; tile[r][cs + 3] = v.w;
  __syncthreads();
  float4 o;
  o.x = tile[cs + 0][r]; o.y = tile[cs + 1][r];
  o.z = tile[cs + 2][r]; o.w = tile[cs + 3][r];
  *(float4*)&D[(size_t)(c0 + r) * HARM + r0 + cs] = o;
}

// --------------- split-K resonance: Rp[kc][M][64] += X[M][Kc] * BT[Kc][64]
__global__ __launch_bounds__(256) void resonance_split(
    const float* __restrict__ X,
    const float* __restrict__ B0, const float* __restrict__ B1,
    const float* __restrict__ B2,
    float* __restrict__ R0, float* __restrict__ R1, float* __restrict__ R2) {
  const int z = blockIdx.z;
  const float* BT = (z == 0) ? B0 : (z == 1) ? B1 : B2;
  float* Rp = (z == 0) ? R0 : (z == 1) ? R1 : R2;
  const int row0 = blockIdx.x * 64;
  const int kc = blockIdx.y;
  __shared__ float Xt[32][68];   // [kk][row]
  __shared__ float Bt[32][68];   // [kk][col]
  const int tid = threadIdx.x;
  const int ty = tid >> 4, tx = tid & 15;
  float acc[4][4] = {};
  const int kbase = kc * 512;
  for (int k0 = kbase; k0 < kbase + 512; k0 += 32) {
    #pragma unroll
    for (int i = 0; i < 8; ++i) {
      int idx = tid + i * 256;
      int r = idx >> 5, kk = idx & 31;
      Xt[kk][r] = X[(size_t)(row0 + r) * HIDDEN + k0 + kk];
      int rb = idx & 63, kb = idx >> 6;
      Bt[kb][rb] = BT[(size_t)(k0 + kb) * HARM + rb];
    }
    __syncthreads();
    #pragma unroll
    for (int kk = 0; kk < 32; ++kk) {
      float4 xv = *(const float4*)&Xt[kk][ty * 4];
      float4 bv = *(const float4*)&Bt[kk][tx * 4];
      acc[0][0] += xv.x * bv.x; acc[0][1] += xv.x * bv.y; acc[0][2] += xv.x * bv.z; acc[0][3] += xv.x * bv.w;
      acc[1][0] += xv.y * bv.x; acc[1][1] += xv.y * bv.y; acc[1][2] += xv.y * bv.z; acc[1][3] += xv.y * bv.w;
      acc[2][0] += xv.z * bv.x; acc[2][1] += xv.z * bv.y; acc[2][2] += xv.z * bv.z; acc[2][3] += xv.z * bv.w;
      acc[3][0] += xv.w * bv.x; acc[3][1] += xv.w * bv.y; acc[3][2] += xv.w * bv.z; acc[3][3] += xv.w * bv.w;
    }
    __syncthreads();
  }
  #pragma unroll
  for (int i = 0; i < 4; ++i) {
    float4 v = make_float4(acc[i][0], acc[i][1], acc[i][2], acc[i][3]);
    *(float4*)&Rp[(size_t)(kc * ROWS + row0 + ty * 4 + i) * HARM + tx * 4] = v;
  }
}

// --------------- projection: P[M][2048] = (sum_kc Rp[kc]) [M][64] * WT[64][2048]
__global__ __launch_bounds__(256) void proj_bf16_f(
    const float* __restrict__ Rp0, const float* __restrict__ Rp1,
    const float* __restrict__ Rp2,
    const float* __restrict__ T0, const float* __restrict__ T1,
    const float* __restrict__ T2,
    ushort* __restrict__ P0, ushort* __restrict__ P1, ushort* __restrict__ P2) {
  const int z = blockIdx.z;
  const float* Rp = (z == 0) ? Rp0 : (z == 1) ? Rp1 : Rp2;
  const float* WT = (z == 0) ? T0 : (z == 1) ? T1 : T2;
  ushort* P = (z == 0) ? P0 : (z == 1) ? P1 : P2;
  const int row0 = blockIdx.x * 32;
  const int col0 = blockIdx.y * 128;
  __shared__ float Rt[64][36];
  __shared__ float Wt[64][132];
  const int tid = threadIdx.x;
  #pragma unroll
  for (int i = 0; i < 8; ++i) {
    int idx = tid + i * 256;
    int r = idx >> 6, kk = idx & 63;
    size_t o = (size_t)(row0 + r) * HARM + kk;
    Rt[kk][r] = Rp[o] + Rp[RN + o] + Rp[2 * (size_t)RN + o] + Rp[3 * (size_t)RN + o];
  }
  #pragma unroll
  for (int i = 0; i < 32; ++i) {
    int idx = tid + i * 256;
    int c = idx & 127, kk = idx >> 7;
    Wt[kk][c] = WT[(size_t)kk * HIDDEN + col0 + c];
  }
  __syncthreads();
  const int ty = tid >> 5, tx = tid & 31;
  float acc[4][4] = {};
  #pragma unroll
  for (int kk = 0; kk < 64; ++kk) {
    float4 rv = *(const float4*)&Rt[kk][ty * 4];
    float4 wv = *(const float4*)&Wt[kk][tx * 4];
    acc[0][0] += rv.x * wv.x; acc[0][1] += rv.x * wv.y; acc[0][2] += rv.x * wv.z; acc[0][3] += rv.x * wv.w;
    acc[1][0] += rv.y * wv.x; acc[1][1] += rv.y * wv.y; acc[1][2] += rv.y * wv.z; acc[1][3] += rv.y * wv.w;
    acc[2][0] += rv.z * wv.x; acc[2][1] += rv.z * wv.y; acc[2][2] += rv.z * wv.z; acc[2][3] += rv.z * wv.w;
    acc[3][0] += rv.w * wv.x; acc[3][1] += rv.w * wv.y; acc[3][2] += rv.w * wv.z; acc[3][3] += rv.w * wv.w;
  }
  #pragma unroll
  for (int i = 0; i < 4; ++i) {
    union { ushort4 s; __hip_bfloat16 b[4]; } cv;
    cv.b[0] = __float2bfloat16(acc[i][0]); cv.b[1] = __float2bfloat16(acc[i][1]);
    cv.b[2] = __float2bfloat16(acc[i][2]); cv.b[3] = __float2bfloat16(acc[i][3]);
    *(ushort4*)&P[(size_t)(row0 + ty * 4 + i) * HIDDEN + col0 + tx * 4] = cv.s;
  }
}

// fp32-output single variant (final o-projection), grid (128, 16)
__global__ __launch_bounds__(256) void proj_f32(
    const float* __restrict__ Rp, const float* __restrict__ WT,
    float* __restrict__ P) {
  const int row0 = blockIdx.x * 32;
  const int col0 = blockIdx.y * 128;
  __shared__ float Rt[64][36];
  __shared__ float Wt[64][132];
  const int tid = threadIdx.x;
  #pragma unroll
  for (int i = 0; i < 8; ++i) {
    int idx = tid + i * 256;
    int r = idx >> 6, kk = idx & 63;
    size_t o = (size_t)(row0 + r) * HARM + kk;
    Rt[kk][r] = Rp[o] + Rp[RN + o] + Rp[2 * (size_t)RN + o] + Rp[3 * (size_t)RN + o];
  }
  #pragma unroll
  for (int i = 0; i < 32; ++i) {
    int idx = tid + i * 256;
    int c = idx & 127, kk = idx >> 7;
    Wt[kk][c] = WT[(size_t)kk * HIDDEN + col0 + c];
  }
  __syncthreads();
  const int ty = tid >> 5, tx = tid & 31;
  float acc[4][4] = {};
  #pragma unroll
  for (int kk = 0; kk < 64; ++kk) {
    float4 rv = *(const float4*)&Rt[kk][ty * 4];
    float4 wv = *(const float4*)&Wt[kk][tx * 4];
    acc[0][0] += rv.x * wv.x; acc[0][1] += rv.x * wv.y; acc[0][2] += rv.x * wv.z; acc[0][3] += rv.x * wv.w;
    acc[1][0] += rv.y * wv.x; acc[1][1] += rv.y * wv.y; acc[1][2] += rv.y * wv.z; acc[1][3] += rv.y * wv.w;
    acc[2][0] += rv.z * wv.x; acc[2][1] += rv.z * wv.y; acc[2][2] += rv.z * wv.z; acc[2][3] += rv.z * wv.w;
    acc[3][0] += rv.w * wv.x; acc[3][1] += rv.w * wv.y; acc[3][2] += rv.w * wv.z; acc[3][3] += rv.w * wv.w;
  }
  #pragma unroll
  for (int i = 0; i < 4; ++i) {
    float4 v = make_float4(acc[i][0], acc[i][1], acc[i][2], acc[i][3]);
    *(float4*)&P[(size_t)(row0 + ty * 4 + i) * HIDDEN + col0 + tx * 4] = v;
  }
}

// -------------------------------------- per-batch 2048x2048 bf16 transpose (V -> V^T)
__global__ __launch_bounds__(256) void transpose_v(
    const ushort* __restrict__ S, ushort* __restrict__ D) {
  const int b = blockIdx.z;
  const int r0 = blockIdx.y * 32, c0 = blockIdx.x * 32;
  __shared__ ushort tile[32][33];
  const int t = threadIdx.x;
  const int r = t >> 3, cs = (t & 7) * 4;
  const ushort* Sb = S + (size_t)b * SEQ * HIDDEN;
  ushort* Db = D + (size_t)b * SEQ * HIDDEN;
  ushort4 v = *(const ushort4*)&Sb[(size_t)(r0 + r) * HIDDEN + c0 + cs];
  tile[r][cs] = v.x; tile[r][cs + 1] = v.y; tile[r][cs + 2] = v.z; tile[r][cs + 3] = v.w;
  __syncthreads();
  ushort4 o;
  o.x = tile[cs + 0][r]; o.y = tile[cs + 1][r];
  o.z = tile[cs + 2][r]; o.w = tile[cs + 3][r];
  *(ushort4*)&Db[(size_t)(c0 + r) * SEQ + r0 + cs] = o;
}

// ----------------------------------------------------------- MFMA flash attention
// 512-thread blocks: two 4-wave groups, each processes alternating 64-key chunks
// into its own KV LDS buffer -> 16 waves/CU (vs 8). 2-way flash merge via LDS.
#define BQ 128
#define BK 64
#define KSTR 136
#define VSTR 72

__device__ inline unsigned pkbf(float a, float b) {
  __hip_bfloat162 h2 = __float22bfloat162_rn(make_float2(a, b));
  union { __hip_bfloat162 h; unsigned u; } cv; cv.h = h2; return cv.u;
}

__global__ __launch_bounds__(512, 4) void attn_mfma(
    const ushort* __restrict__ Qg, const ushort* __restrict__ Kg,
    const ushort* __restrict__ Vt, float* __restrict__ O) {
  __shared__ __align__(16) union SM {
    ushort q[BQ][KSTR];                                     // 34816 B
    struct { ushort k[2][BK][KSTR]; ushort v[2][HDIM][VSTR]; } kv;  // 71680 B
    struct { float o[256][68]; float ml[128][2]; } mg;      // 70656 B
  } sm;
  const int t = threadIdx.x;
  const int t256 = t & 255;
  const int grp = t >> 8;
  const int bh = blockIdx.x & 31;
  const int qt = blockIdx.x >> 5;
  const int b = bh >> 4, h = bh & 15;
  const int q0 = qt * BQ;
  const int lane = t & 63;
  const int w4 = (t >> 6) & 3;           // wave index within group
  const int l31 = lane & 31;
  const int hh = lane >> 5;
  const bool hi = (hh != 0);
  const float SC2 = 0.08838834764831845f * 1.4426950408889634f;  // scale*log2(e)

  // ---- stage Q tile (all 512 threads), pull B-fragments, then free the space
  {
    const size_t gbase = ((size_t)(b * SEQ + q0)) * HIDDEN + h * HDIM;
    #pragma unroll
    for (int p = 0; p < 4; ++p) {
      int row = p * 32 + (t >> 4);
      int d0 = (t & 15) * 8;
      uint4 v = *(const uint4*)&Qg[gbase + (size_t)row * HIDDEN + d0];
      *(uint4*)&sm.q[row][d0] = v;
    }
  }
  __syncthreads();
  bf16x8 Qf[8];
  {
    const int qrow = w4 * 32 + l31;
    #pragma unroll
    for (int ks = 0; ks < 8; ++ks)
      Qf[ks] = *(const bf16x8*)&sm.q[qrow][ks * 16 + 8 * hh];
  }
  __syncthreads();

  float mrow = -1e30f, lsum = 0.0f;
  f32x16 Ot[4];
  #pragma unroll
  for (int i = 0; i < 4; ++i)
    #pragma unroll
    for (int j = 0; j < 16; ++j) Ot[i][j] = 0.0f;

  for (int ci = 0; ci < 16; ++ci) {
    const int k0 = ci * 128 + grp * 64;   // interleaved chunks per group
    // ---- stage this group's K chunk + V^T chunk (256 threads each)
    {
      const size_t gb = ((size_t)(b * SEQ + k0)) * HIDDEN + h * HDIM;
      #pragma unroll
      for (int p = 0; p < 4; ++p) {
        int key = p * 16 + (t256 >> 4);
        int d0 = (t256 & 15) * 8;
        uint4 v = *(const uint4*)&Kg[gb + (size_t)key * HIDDEN + d0];
        *(uint4*)&sm.kv.k[grp][key][d0] = v;
      }
      const size_t vb = ((size_t)(b * SEQ + h * HDIM)) * SEQ + k0;
      #pragma unroll
      for (int p = 0; p < 4; ++p) {
        int d = p * 32 + (t256 >> 3);
        int ks2 = (t256 & 7) * 8;
        uint4 v = *(const uint4*)&Vt[vb + (size_t)d * SEQ + ks2];
        *(uint4*)&sm.kv.v[grp][d][ks2] = v;
      }
    }
    __syncthreads();

    // ---- S^T = K . Q^T
    f32x16 C0, C1;
    #pragma unroll
    for (int j = 0; j < 16; ++j) { C0[j] = 0.0f; C1[j] = 0.0f; }
    #pragma unroll
    for (int ks = 0; ks < 8; ++ks) {
      bf16x8 a0 = *(const bf16x8*)&sm.kv.k[grp][l31][ks * 16 + 8 * hh];
      bf16x8 a1 = *(const bf16x8*)&sm.kv.k[grp][32 + l31][ks * 16 + 8 * hh];
      C0 = __builtin_amdgcn_mfma_f32_32x32x16_bf16(a0, Qf[ks], C0, 0, 0, 0);
      C1 = __builtin_amdgcn_mfma_f32_32x32x16_bf16(a1, Qf[ks], C1, 0, 0, 0);
    }

    // ---- online softmax
    float mxr = -1e30f;
    #pragma unroll
    for (int j = 0; j < 16; ++j) mxr = fmaxf(mxr, fmaxf(C0[j], C1[j]));
    mxr = fmaxf(mxr, __shfl_xor(mxr, 32));
    const float mnew = fmaxf(mrow, mxr * SC2);
    const float alpha = exp2f(mrow - mnew);
    float ssum = 0.0f;
    #pragma unroll
    for (int j = 0; j < 16; ++j) {
      float e0 = exp2f(fmaf(C0[j], SC2, -mnew));
      float e1 = exp2f(fmaf(C1[j], SC2, -mnew));
      C0[j] = e0; C1[j] = e1;
      ssum += e0 + e1;
    }
    ssum += __shfl_xor(ssum, 32);
    lsum = lsum * alpha + ssum;
    mrow = mnew;
    #pragma unroll
    for (int i = 0; i < 4; ++i)
      #pragma unroll
      for (int j = 0; j < 16; ++j) Ot[i][j] *= alpha;

    // ---- O^T += V^T . P^T
    #pragma unroll
    for (int st = 0; st < 4; ++st) {
      const int eb = 8 * (st & 1);
      float o0, o1, o2, o3, g0, g1, g2, g3;
      if (st < 2) {
        o0 = hi ? C0[eb + 4] : C0[eb + 0]; o1 = hi ? C0[eb + 5] : C0[eb + 1];
        o2 = hi ? C0[eb + 6] : C0[eb + 2]; o3 = hi ? C0[eb + 7] : C0[eb + 3];
        g0 = hi ? C0[eb + 0] : C0[eb + 4]; g1 = hi ? C0[eb + 1] : C0[eb + 5];
        g2 = hi ? C0[eb + 2] : C0[eb + 6]; g3 = hi ? C0[eb + 3] : C0[eb + 7];
      } else {
        o0 = hi ? C1[eb + 4] : C1[eb + 0]; o1 = hi ? C1[eb + 5] : C1[eb + 1];
        o2 = hi ? C1[eb + 6] : C1[eb + 2]; o3 = hi ? C1[eb + 7] : C1[eb + 3];
        g0 = hi ? C1[eb + 0] : C1[eb + 4]; g1 = hi ? C1[eb + 1] : C1[eb + 5];
        g2 = hi ? C1[eb + 2] : C1[eb + 6]; g3 = hi ? C1[eb + 3] : C1[eb + 7];
      }
      unsigned so0 = pkbf(o0, o1), so1 = pkbf(o2, o3);
      unsigned sp0 = pkbf(g0, g1), sp1 = pkbf(g2, g3);
      unsigned r0 = (unsigned)__shfl_xor((int)sp0, 32);
      unsigned r1 = (unsigned)__shfl_xor((int)sp1, 32);
      union { unsigned u[4]; bf16x8 v; } cv;
      cv.u[0] = hi ? r0 : so0;
      cv.u[1] = hi ? r1 : so1;
      cv.u[2] = hi ? so0 : r0;
      cv.u[3] = hi ? so1 : r1;
      #pragma unroll
      for (int mt = 0; mt < 4; ++mt) {
        bf16x8 a2 = *(const bf16x8*)&sm.kv.v[grp][mt * 32 + l31][st * 16 + 8 * hh];
        Ot[mt] = __builtin_amdgcn_mfma_f32_32x32x16_bf16(a2, cv.v, Ot[mt], 0, 0, 0);
      }
    }
    __syncthreads();
  }

  // ---- 2-way flash merge between the groups (grp1 publishes, grp0 combines)
  if (grp == 1) {
    if (hh == 0) {
      sm.mg.ml[w4 * 32 + l31][0] = mrow;
      sm.mg.ml[w4 * 32 + l31][1] = lsum;
    }
    const int li = w4 * 64 + lane;
    #pragma unroll
    for (int mt = 0; mt < 4; ++mt)
      #pragma unroll
      for (int g = 0; g < 4; ++g)
        *(float4*)&sm.mg.o[li][mt * 16 + g * 4] =
            make_float4(Ot[mt][4 * g + 0], Ot[mt][4 * g + 1],
                        Ot[mt][4 * g + 2], Ot[mt][4 * g + 3]);
  }
  __syncthreads();
  if (grp == 0) {
    const float m1 = sm.mg.ml[w4 * 32 + l31][0];
    const float l1 = sm.mg.ml[w4 * 32 + l31][1];
    const float ms = fmaxf(mrow, m1);
    const float a0 = exp2f(mrow - ms);
    const float a1 = exp2f(m1 - ms);
    const float inv = 1.0f / (lsum * a0 + l1 * a1);
    const int li = w4 * 64 + lane;
    const int qrow = q0 + w4 * 32 + l31;
    float* ob = O + ((size_t)(b * SEQ + qrow)) * HIDDEN + h * HDIM;
    #pragma unroll
    for (int mt = 0; mt < 4; ++mt)
      #pragma unroll
      for (int g = 0; g < 4; ++g) {
        float4 o1 = *(const float4*)&sm.mg.o[li][mt * 16 + g * 4];
        float4 vv = make_float4(
            (Ot[mt][4 * g + 0] * a0 + o1.x * a1) * inv,
            (Ot[mt][4 * g + 1] * a0 + o1.y * a1) * inv,
            (Ot[mt][4 * g + 2] * a0 + o1.z * a1) * inv,
            (Ot[mt][4 * g + 3] * a0 + o1.w * a1) * inv);
        *(float4*)&ob[mt * 32 + 8 * g + 4 * hh] = vv;
      }
  }
}

// -------------------------------------------------------------------------- launcher
extern "C" void kernel_launch(void* const* d_in, const int* in_sizes, int n_in,
                              void* d_out, int out_size, void* d_ws, size_t ws_size,
                              hipStream_t stream) {
  (void)in_sizes; (void)n_in; (void)out_size; (void)ws_size;
  const float* X       = (const float*)d_in[0];
  const float* basis_q = (const float*)d_in[1];
  const float* phase_q = (const float*)d_in[2];
  const float* amp_q   = (const float*)d_in[3];
  const float* basis_k = (const float*)d_in[4];
  const float* phase_k = (const float*)d_in[5];
  const float* amp_k   = (const float*)d_in[6];
  const float* basis_v = (const float*)d_in[7];
  const float* phase_v = (const float*)d_in[8];
  const float* amp_v   = (const float*)d_in[9];
  const float* basis_o = (const float*)d_in[10];
  const float* phase_o = (const float*)d_in[11];
  const float* amp_o   = (const float*)d_in[12];

  const size_t WN = (size_t)HIDDEN * HARM;   // 131072
  const size_t PN = (size_t)ROWS * HIDDEN;   // 8388608

  char* p = (char*)d_ws;
  float* WTq = (float*)p; p += WN * 4;
  float* WTk = (float*)p; p += WN * 4;
  float* WTv = (float*)p; p += WN * 4;
  float* WTo = (float*)p; p += WN * 4;
  float* BTq = (float*)p; p += WN * 4;
  float* BTk = (float*)p; p += WN * 4;
  float* BTv = (float*)p; p += WN * 4;
  float* BTo = (float*)p; p += WN * 4;
  float* Rqp = (float*)p; p += (size_t)4 * RN * 4;
  float* Rkp = (float*)p; p += (size_t)4 * RN * 4;
  float* Rvp = (float*)p; p += (size_t)4 * RN * 4;
  float* Rop = (float*)p; p += (size_t)4 * RN * 4;
  __hip_bfloat16* Qb = (__hip_bfloat16*)p; p += PN * 2;
  __hip_bfloat16* Kb = (__hip_bfloat16*)p; p += PN * 2;
  __hip_bfloat16* Vb = (__hip_bfloat16*)p; p += PN * 2;
  __hip_bfloat16* VtB = (__hip_bfloat16*)p; p += PN * 2;
  float* AO = (float*)p; p += PN * 4;
  float* out = (float*)d_out;

  wt_kernel<<<2048, 256, 0, stream>>>(phase_q, amp_q, phase_k, amp_k,
                                      phase_v, amp_v, phase_o, amp_o,
                                      WTq, WTk, WTv, WTo);
  transpose_basis<<<dim3(64, 2, 4), 256, 0, stream>>>(
      basis_q, basis_k, basis_v, basis_o, BTq, BTk, BTv, BTo);

  resonance_split<<<dim3(64, 4, 3), 256, 0, stream>>>(
      X, BTq, BTk, BTv, Rqp, Rkp, Rvp);

  proj_bf16_f<<<dim3(128, 16, 3), 256, 0, stream>>>(
      Rqp, Rkp, Rvp, WTq, WTk, WTv,
      (ushort*)Qb, (ushort*)Kb, (ushort*)Vb);

  transpose_v<<<dim3(HIDDEN / 32, SEQ / 32, BATCH), 256, 0, stream>>>(
      (const ushort*)Vb, (ushort*)VtB);

  attn_mfma<<<dim3((SEQ / BQ) * 32), 512, 0, stream>>>(
      (const ushort*)Qb, (const ushort*)Kb, (const ushort*)VtB, AO);

  resonance_split<<<dim3(64, 4, 1), 256, 0, stream>>>(
      AO, BTo, BTo, BTo, Rop, Rop, Rop);

  proj_f32<<<dim3(128, 16), 256, 0, stream>>>(Rop, WTo, out);
}